// Round 15
// baseline (337.838 us; speedup 1.0000x reference)
//
#include <hip/hip_runtime.h>
#include <math.h>

// EmbeddingEncoder: B=128, S=384, D=96, H=4, K=7, L=4.
// Round 15: pass-2 software pipelining in attention — score(c+1) MFMAs issued
// between P-write(c) and PV-read(c) (double-buffered wave-private P in LDS).
// Rest identical to round 14 (VGPR cap 256 via launch_bounds(256,2), no spills).

constexpr int B = 128;
constexpr int S = 384;
constexpr int D = 96;
constexpr int H = 4;
constexpr int KW = 7;
constexpr int L = 4;
constexpr int ROWS = B * S;                      // 49152
constexpr long long NTOT = (long long)ROWS * D;  // 4718592
constexpr float SQRTD = 9.797958971132712f;

typedef _Float16 f16x8 __attribute__((ext_vector_type(8)));
typedef float f32x4 __attribute__((ext_vector_type(4)));
typedef unsigned short us;
typedef unsigned short us8 __attribute__((ext_vector_type(8)));

__device__ __forceinline__ us f2h(float f) {
    _Float16 h = (_Float16)f;
    return __builtin_bit_cast(us, h);
}
__device__ __forceinline__ f16x8 ldh(const us* p) {
    return *reinterpret_cast<const f16x8*>(p);
}

// ---------------- positional encoding ----------------
__global__ void pe_kernel(float* __restrict__ pe) {
    int idx = blockIdx.x * 256 + threadIdx.x;
    if (idx >= S * D) return;
    int s = idx / D, c = idx - s * D;
    int j = c >> 1;
    float expo = (c & 1) ? (4.0f * j + 2.0f) / 96.0f : (4.0f * j) / 96.0f;
    float freq = expf(-expo * logf(10000.0f));
    float ang = (float)s * freq;
    pe[idx] = (c & 1) ? cosf(ang) : sinf(ang);
}

// ---------------- weight prep ----------------
__global__ void prep_w(const float* __restrict__ WQ, const float* __restrict__ WK,
                       const float* __restrict__ cpw, const float* __restrict__ w1,
                       const float* __restrict__ w2,
                       us* __restrict__ wqS, us* __restrict__ wkT, us* __restrict__ pw16,
                       us* __restrict__ w1T, us* __restrict__ w2Tp) {
    int idx = blockIdx.x * 256 + threadIdx.x;
    if (idx >= H * D * D) return;  // 36864
    int h = idx / (D * D), rem = idx - h * (D * D);
    int d = rem / D, e = rem - d * D;
    int n = e >> 4, lmod = e & 15, kk = d >> 5, ldiv = (d >> 3) & 3, j = d & 7;
    wqS[(size_t)(((h * 6 + n) * 3 + kk) * 64 + ldiv * 16 + lmod) * 8 + j] = f2h(WQ[idx] * SQRTD);
    wkT[(size_t)h * D * D + e * D + d] = f2h(WK[idx]);
    pw16[idx] = f2h(cpw[idx]);  // L*D*D == 36864
    if (idx < 48 * 96) {
        int m = idx / 96, c = idx - m * 96;
        w1T[idx] = f2h(w1[c * 48 + m]);
    }
    if (idx < 96 * 64) {
        int o = idx / 64, m = idx - o * 64;
        w2Tp[idx] = (m < 48) ? f2h(w2[m * 96 + o]) : (us)0;
    }
}

// ---------------- WVO_h = WV_h @ WO_h, stored transposed [h][o][d] ----------------
__global__ void prep_wvo(const float* __restrict__ WV, const float* __restrict__ WO,
                         us* __restrict__ wvoT) {
    int blk = blockIdx.x;  // 24 = H * 6
    int h = blk / 6, ot = blk - h * 6;
    int tid = threadIdx.x;
    const float* wv = WV + (size_t)h * D * D;
    const float* wo = WO + (size_t)h * D * D;
    for (int i = tid; i < 16 * 96; i += 256) {
        int o = ot * 16 + i / 96, d = i - (i / 96) * 96;
        float acc = 0.f;
        for (int e = 0; e < 96; e++) acc += wv[d * 96 + e] * wo[e * 96 + o];
        wvoT[(size_t)h * D * D + o * 96 + d] = f2h(acc);
    }
}

// ---------------- conv0: embed + LN0 (halo inline) + dw + pw + residual + LN1 ----------------
__global__ void conv0f(const float* __restrict__ in, const float* __restrict__ pe,
                       const float* __restrict__ g0, const float* __restrict__ b0,
                       float* __restrict__ xout, us* __restrict__ lnout,
                       const float* __restrict__ dwW, const float* __restrict__ dwB,
                       const us* __restrict__ pwW, const float* __restrict__ pwb,
                       const float* __restrict__ gnext, const float* __restrict__ bnext) {
    __shared__ us lnb_s[70 * 104];
    __shared__ us dwb_s[64 * 104];
    __shared__ float lw[96 * 8];
    int tid = threadIdx.x;
    int wave = tid >> 6, lane = tid & 63;
    int r0 = blockIdx.x * 64;
    int b = r0 / S, s0 = r0 % S;

    for (int i = tid; i < 96 * KW; i += 256) lw[(i / KW) * 8 + (i % KW)] = dwW[i];

    for (int i = wave; i < 70; i += 4) {
        int s = s0 - 3 + i;
        bool valid = (unsigned)s < (unsigned)S;
        float v0 = 0.f, v1 = 0.f;
        if (valid) {
            size_t ro = ((size_t)b * S + s) * 96;
            v0 = in[ro + lane] * SQRTD + pe[s * 96 + lane];
            v1 = (lane < 32) ? in[ro + 64 + lane] * SQRTD + pe[s * 96 + 64 + lane] : 0.f;
        }
        float sm = v0 + v1, q = v0 * v0 + v1 * v1;
        for (int off = 32; off > 0; off >>= 1) {
            sm += __shfl_xor(sm, off);
            q += __shfl_xor(q, off);
        }
        float mean = sm * (1.0f / D);
        float var = q * (1.0f / D) - mean * mean;
        float rstd = rsqrtf(var + 1e-5f);
        lnb_s[i * 104 + lane] = f2h(valid ? (v0 - mean) * rstd * g0[lane] + b0[lane] : 0.f);
        if (lane < 32)
            lnb_s[i * 104 + 64 + lane] =
                f2h(valid ? (v1 - mean) * rstd * g0[lane + 64] + b0[lane + 64] : 0.f);
    }
    __syncthreads();

    for (int u = tid; u < 768; u += 256) {
        int j = u / 12, c0 = (u - (u / 12) * 12) * 8;
        float acc[8];
        #pragma unroll
        for (int j2 = 0; j2 < 8; j2++) acc[j2] = dwB[c0 + j2];
        #pragma unroll
        for (int k = 0; k < KW; k++) {
            f16x8 v = ldh(&lnb_s[(j + k) * 104 + c0]);
            #pragma unroll
            for (int j2 = 0; j2 < 8; j2++) acc[j2] += (float)v[j2] * lw[(c0 + j2) * 8 + k];
        }
        us8 o;
        #pragma unroll
        for (int j2 = 0; j2 < 8; j2++) o[j2] = f2h(acc[j2]);
        *reinterpret_cast<us8*>(&dwb_s[j * 104 + c0]) = o;
    }
    __syncthreads();

    int lmod = lane & 15, ldiv = lane >> 4, m0 = wave * 16;
    f32x4 acc[6] = {};
    #pragma unroll
    for (int kk = 0; kk < 3; kk++) {
        f16x8 af = ldh(&dwb_s[(m0 + lmod) * 104 + kk * 32 + ldiv * 8]);
        #pragma unroll
        for (int n = 0; n < 6; n++) {
            f16x8 bf = ldh(pwW + (size_t)(n * 16 + lmod) * 96 + kk * 32 + ldiv * 8);
            acc[n] = __builtin_amdgcn_mfma_f32_16x16x32_f16(af, bf, acc[n], 0, 0, 0);
        }
    }

    float gv[6], bv2[6], pb[6];
    #pragma unroll
    for (int n = 0; n < 6; n++) {
        int o = n * 16 + lmod;
        gv[n] = gnext[o];
        bv2[n] = bnext[o];
        pb[n] = pwb[o];
    }
    #pragma unroll
    for (int n = 0; n < 6; n++) {
        int o = n * 16 + lmod;
        #pragma unroll
        for (int r = 0; r < 4; r++) {
            int sr = m0 + ldiv * 4 + r;
            size_t row = (size_t)r0 + sr;
            float base = in[row * 96 + o] * SQRTD + pe[(s0 + sr) * 96 + o];
            acc[n][r] = base + fmaxf(acc[n][r] + pb[n], 0.f);
        }
    }
    #pragma unroll
    for (int r = 0; r < 4; r++) {
        float sm = 0.f, qq = 0.f;
        #pragma unroll
        for (int n = 0; n < 6; n++) {
            sm += acc[n][r];
            qq += acc[n][r] * acc[n][r];
        }
        #pragma unroll
        for (int st = 1; st <= 8; st <<= 1) {
            sm += __shfl_xor(sm, st);
            qq += __shfl_xor(qq, st);
        }
        float mean = sm * (1.0f / D);
        float var = qq * (1.0f / D) - mean * mean;
        float rstd = rsqrtf(var + 1e-5f);
        size_t row = (size_t)r0 + m0 + ldiv * 4 + r;
        #pragma unroll
        for (int n = 0; n < 6; n++) {
            int o = n * 16 + lmod;
            xout[row * 96 + o] = acc[n][r];
            lnout[row * 96 + o] = f2h((acc[n][r] - mean) * rstd * gv[n] + bv2[n]);
        }
    }
}

// ---------------- mid conv layer: dw(lnin global f16) -> pw -> residual -> LN_next ----------------
__global__ void conv2(const float* __restrict__ xin, const us* __restrict__ lnin,
                      float* __restrict__ xout, us* __restrict__ lnout,
                      const float* __restrict__ dwW, const float* __restrict__ dwB,
                      const us* __restrict__ pwW, const float* __restrict__ pwb,
                      const float* __restrict__ gnext, const float* __restrict__ bnext) {
    __shared__ us dwb_s[64 * 104];
    __shared__ float lw[96 * 8];
    int tid = threadIdx.x;
    int wave = tid >> 6, lane = tid & 63;
    int r0 = blockIdx.x * 64;
    int b = r0 / S, s0 = r0 % S;

    for (int i = tid; i < 96 * KW; i += 256) lw[(i / KW) * 8 + (i % KW)] = dwW[i];
    __syncthreads();

    for (int u = tid; u < 768; u += 256) {
        int j = u / 12, c0 = (u - (u / 12) * 12) * 8;
        float acc[8];
        #pragma unroll
        for (int j2 = 0; j2 < 8; j2++) acc[j2] = dwB[c0 + j2];
        #pragma unroll
        for (int k = 0; k < KW; k++) {
            int ss = s0 + j + k - 3;
            if ((unsigned)ss < (unsigned)S) {
                f16x8 v = ldh(lnin + ((size_t)b * S + ss) * 96 + c0);
                #pragma unroll
                for (int j2 = 0; j2 < 8; j2++) acc[j2] += (float)v[j2] * lw[(c0 + j2) * 8 + k];
            }
        }
        us8 o;
        #pragma unroll
        for (int j2 = 0; j2 < 8; j2++) o[j2] = f2h(acc[j2]);
        *reinterpret_cast<us8*>(&dwb_s[j * 104 + c0]) = o;
    }
    __syncthreads();

    int lmod = lane & 15, ldiv = lane >> 4, m0 = wave * 16;
    f32x4 acc[6] = {};
    #pragma unroll
    for (int kk = 0; kk < 3; kk++) {
        f16x8 af = ldh(&dwb_s[(m0 + lmod) * 104 + kk * 32 + ldiv * 8]);
        #pragma unroll
        for (int n = 0; n < 6; n++) {
            f16x8 bf = ldh(pwW + (size_t)(n * 16 + lmod) * 96 + kk * 32 + ldiv * 8);
            acc[n] = __builtin_amdgcn_mfma_f32_16x16x32_f16(af, bf, acc[n], 0, 0, 0);
        }
    }

    float gv[6], bv2[6], pb[6];
    #pragma unroll
    for (int n = 0; n < 6; n++) {
        int o = n * 16 + lmod;
        gv[n] = gnext[o];
        bv2[n] = bnext[o];
        pb[n] = pwb[o];
    }
    #pragma unroll
    for (int n = 0; n < 6; n++) {
        #pragma unroll
        for (int r = 0; r < 4; r++) {
            size_t row = (size_t)r0 + m0 + ldiv * 4 + r;
            acc[n][r] = xin[row * 96 + n * 16 + lmod] + fmaxf(acc[n][r] + pb[n], 0.f);
        }
    }
    #pragma unroll
    for (int r = 0; r < 4; r++) {
        float sm = 0.f, qq = 0.f;
        #pragma unroll
        for (int n = 0; n < 6; n++) {
            sm += acc[n][r];
            qq += acc[n][r] * acc[n][r];
        }
        #pragma unroll
        for (int st = 1; st <= 8; st <<= 1) {
            sm += __shfl_xor(sm, st);
            qq += __shfl_xor(qq, st);
        }
        float mean = sm * (1.0f / D);
        float var = qq * (1.0f / D) - mean * mean;
        float rstd = rsqrtf(var + 1e-5f);
        size_t row = (size_t)r0 + m0 + ldiv * 4 + r;
        #pragma unroll
        for (int n = 0; n < 6; n++) {
            int o = n * 16 + lmod;
            xout[row * 96 + o] = acc[n][r];
            lnout[row * 96 + o] = f2h((acc[n][r] - mean) * rstd * gv[n] + bv2[n]);
        }
    }
}

// ---------------- conv3 + K/V' projection fused ----------------
__global__ void conv3p(const float* __restrict__ xin, const us* __restrict__ lnin,
                       float* __restrict__ xout, us* __restrict__ lnout,
                       const float* __restrict__ dwW, const float* __restrict__ dwB,
                       const us* __restrict__ pwW, const float* __restrict__ pwb,
                       const float* __restrict__ gnext, const float* __restrict__ bnext,
                       const us* __restrict__ wkT, const us* __restrict__ wvoT,
                       us* __restrict__ Kall, us* __restrict__ Vall) {
    __shared__ float lw[96 * 8];
    __shared__ us stg[96 * 72];     // union: dw buffer [64][104] / proj staging
    __shared__ us lnstg[64 * 104];  // LN'd rows (h16) for proj A-frags
    int tid = threadIdx.x;
    int wave = tid >> 6, lane = tid & 63;
    int lmod = lane & 15, ldiv = lane >> 4, m0 = wave * 16;
    int r0 = blockIdx.x * 64;
    int b = r0 / S, s0 = r0 % S;

    for (int i = tid; i < 96 * KW; i += 256) lw[(i / KW) * 8 + (i % KW)] = dwW[i];
    __syncthreads();

    for (int u = tid; u < 768; u += 256) {
        int j = u / 12, c0 = (u - (u / 12) * 12) * 8;
        float acc[8];
        #pragma unroll
        for (int j2 = 0; j2 < 8; j2++) acc[j2] = dwB[c0 + j2];
        #pragma unroll
        for (int k = 0; k < KW; k++) {
            int ss = s0 + j + k - 3;
            if ((unsigned)ss < (unsigned)S) {
                f16x8 v = ldh(lnin + ((size_t)b * S + ss) * 96 + c0);
                #pragma unroll
                for (int j2 = 0; j2 < 8; j2++) acc[j2] += (float)v[j2] * lw[(c0 + j2) * 8 + k];
            }
        }
        us8 o;
        #pragma unroll
        for (int j2 = 0; j2 < 8; j2++) o[j2] = f2h(acc[j2]);
        *reinterpret_cast<us8*>(&stg[j * 104 + c0]) = o;
    }
    __syncthreads();

    f32x4 acc[6] = {};
    #pragma unroll
    for (int kk = 0; kk < 3; kk++) {
        f16x8 af = ldh(&stg[(m0 + lmod) * 104 + kk * 32 + ldiv * 8]);
        #pragma unroll
        for (int n = 0; n < 6; n++) {
            f16x8 bf = ldh(pwW + (size_t)(n * 16 + lmod) * 96 + kk * 32 + ldiv * 8);
            acc[n] = __builtin_amdgcn_mfma_f32_16x16x32_f16(af, bf, acc[n], 0, 0, 0);
        }
    }

    float gv[6], bv2[6], pb[6];
    #pragma unroll
    for (int n = 0; n < 6; n++) {
        int o = n * 16 + lmod;
        gv[n] = gnext[o];
        bv2[n] = bnext[o];
        pb[n] = pwb[o];
    }
    #pragma unroll
    for (int n = 0; n < 6; n++) {
        #pragma unroll
        for (int r = 0; r < 4; r++) {
            size_t row = (size_t)r0 + m0 + ldiv * 4 + r;
            acc[n][r] = xin[row * 96 + n * 16 + lmod] + fmaxf(acc[n][r] + pb[n], 0.f);
        }
    }
    #pragma unroll
    for (int r = 0; r < 4; r++) {
        float sm = 0.f, qq = 0.f;
        #pragma unroll
        for (int n = 0; n < 6; n++) {
            sm += acc[n][r];
            qq += acc[n][r] * acc[n][r];
        }
        #pragma unroll
        for (int st = 1; st <= 8; st <<= 1) {
            sm += __shfl_xor(sm, st);
            qq += __shfl_xor(qq, st);
        }
        float mean = sm * (1.0f / D);
        float var = qq * (1.0f / D) - mean * mean;
        float rstd = rsqrtf(var + 1e-5f);
        size_t row = (size_t)r0 + m0 + ldiv * 4 + r;
        #pragma unroll
        for (int n = 0; n < 6; n++) {
            int o = n * 16 + lmod;
            xout[row * 96 + o] = acc[n][r];
            us hv = f2h((acc[n][r] - mean) * rstd * gv[n] + bv2[n]);
            lnout[row * 96 + o] = hv;
            lnstg[(m0 + ldiv * 4 + r) * 104 + o] = hv;
        }
    }
    __syncthreads();

    f16x8 af[3];
    #pragma unroll
    for (int kk = 0; kk < 3; kk++)
        af[kk] = ldh(&lnstg[(m0 + lmod) * 104 + kk * 32 + ldiv * 8]);

    for (int hd = 0; hd < H; hd++) {
        // ---- K ----
        f32x4 ka[6] = {};
        #pragma unroll
        for (int kk = 0; kk < 3; kk++)
            #pragma unroll
            for (int n = 0; n < 6; n++) {
                f16x8 bf =
                    ldh(wkT + (size_t)hd * D * D + (size_t)(n * 16 + lmod) * 96 + kk * 32 + ldiv * 8);
                ka[n] = __builtin_amdgcn_mfma_f32_16x16x32_f16(af[kk], bf, ka[n], 0, 0, 0);
            }
        __syncthreads();
        us* kT = stg + wave * 1664;
        #pragma unroll
        for (int n = 0; n < 6; n++)
            #pragma unroll
            for (int r = 0; r < 4; r++)
                kT[(ldiv * 4 + r) * 104 + n * 16 + lmod] = f2h(ka[n][r]);
        int t0 = (r0 % S) / 16 + wave;
        us* dst = Kall + (size_t)hd * NTOT + ((size_t)(b * 24 + t0) * 3) * 512;
        #pragma unroll
        for (int kk = 0; kk < 3; kk++) {
            us8 v = *reinterpret_cast<const us8*>(&kT[lmod * 104 + kk * 32 + ldiv * 8]);
            *reinterpret_cast<us8*>(dst + kk * 512 + lane * 8) = v;
        }
        // ---- V' ----
        f32x4 va[6] = {};
        #pragma unroll
        for (int kk = 0; kk < 3; kk++)
            #pragma unroll
            for (int n = 0; n < 6; n++) {
                f16x8 bf = ldh(wvoT + (size_t)hd * D * D + (size_t)(n * 16 + lmod) * 96 + kk * 32 +
                               ldiv * 8);
                va[n] = __builtin_amdgcn_mfma_f32_16x16x32_f16(af[kk], bf, va[n], 0, 0, 0);
            }
        __syncthreads();
        #pragma unroll
        for (int n = 0; n < 6; n++)
            #pragma unroll
            for (int r = 0; r < 4; r++)
                stg[(n * 16 + lmod) * 72 + m0 + ldiv * 4 + r] = f2h(va[n][r]);
        __syncthreads();
        int cblk = (r0 % S) / 64;
        us* dsth = Vall + (size_t)hd * NTOT;
        #pragma unroll
        for (int n = 0; n < 6; n++)
            #pragma unroll
            for (int kk = 0; kk < 2; kk++) {
                us8 v =
                    *reinterpret_cast<const us8*>(&stg[(n * 16 + lmod) * 72 + kk * 32 + ldiv * 8]);
                *reinterpret_cast<us8*>(
                    dsth + ((size_t)((b * 6 + n) * 6 + cblk) * 2 + kk) * 512 + lane * 8) = v;
            }
    }
}

// ---------------- two-pass attention, pass-2 software-pipelined ----------------
// grid 1536 x 256 threads; 4 independent waves/block, no barriers.
#define SCORE(CC, S0, S1)                                                                   \
    __builtin_amdgcn_s_setprio(1);                                                          \
    _Pragma("unroll") for (int nt = 0; nt < 4; nt++) {                                      \
        _Pragma("unroll") for (int kk = 0; kk < 3; kk++) {                                  \
            f16x8 bf = ldh(Kh + (size_t)(((CC) * 4 + nt) * 3 + kk) * 512 + lane * 8);       \
            S0[nt] = __builtin_amdgcn_mfma_f32_16x16x32_f16(aq0[kk], bf, S0[nt], 0, 0, 0);  \
            S1[nt] = __builtin_amdgcn_mfma_f32_16x16x32_f16(aq1[kk], bf, S1[nt], 0, 0, 0);  \
        }                                                                                   \
    }                                                                                       \
    __builtin_amdgcn_s_setprio(0);

#define EXPSTORE(S0, S1, BUF)                                      \
    _Pragma("unroll") for (int nt = 0; nt < 4; nt++) {             \
        _Pragma("unroll") for (int r = 0; r < 4; r++) {            \
            float p0 = __expf(S0[nt][r] - mx0[r]);                 \
            float p1 = __expf(S1[nt][r] - mx1[r]);                 \
            l0v[r] += p0;                                          \
            l1v[r] += p1;                                          \
            (BUF)[(ldiv * 4 + r) * 72 + nt * 16 + lmod] = f2h(p0); \
            (BUF)[(16 + ldiv * 4 + r) * 72 + nt * 16 + lmod] = f2h(p1); \
        }                                                          \
    }

#define PVSTEP(CC, BUF)                                                                     \
    __builtin_amdgcn_s_setprio(1);                                                          \
    _Pragma("unroll") for (int kk = 0; kk < 2; kk++) {                                      \
        f16x8 pf0 = ldh((BUF) + lmod * 72 + kk * 32 + ldiv * 8);                            \
        f16x8 pf1 = ldh((BUF) + (16 + lmod) * 72 + kk * 32 + ldiv * 8);                     \
        _Pragma("unroll") for (int n = 0; n < 6; n++) {                                     \
            f16x8 bf = ldh(Vh + (size_t)((n * 6 + (CC)) * 2 + kk) * 512 + lane * 8);        \
            oacc0[n] = __builtin_amdgcn_mfma_f32_16x16x32_f16(pf0, bf, oacc0[n], 0, 0, 0);  \
            oacc1[n] = __builtin_amdgcn_mfma_f32_16x16x32_f16(pf1, bf, oacc1[n], 0, 0, 0);  \
        }                                                                                   \
    }                                                                                       \
    __builtin_amdgcn_s_setprio(0);

__global__ __launch_bounds__(256, 2) void attn_2p4(const us* __restrict__ h16,
                                                   const us* __restrict__ wqS,
                                                   const us* __restrict__ Kall,
                                                   const us* __restrict__ Vall,
                                                   us* __restrict__ xpart) {
    __shared__ us stg4[4][32 * 104];  // Q staging, then P buffer A (stride 72)
    __shared__ us stgP[4][32 * 72];   // P buffer B
    int tid = threadIdx.x, wave = tid >> 6, lane = tid & 63;
    us* stg = stg4[wave];
    us* bufB = stgP[wave];
    int lmod = lane & 15, ldiv = lane >> 4;
    int p = blockIdx.x;
    int gl = (((p & 7) * 192 + (p >> 3)) << 2) + wave;  // 1536 = 8*192, XCD-chunked
    int t = gl % 12;
    int bh = gl / 12;
    int b = bh >> 2, hd = bh & 3;
    size_t rowbase = (size_t)b * S + t * 32;

    f16x8 ah0[3], ah1[3];
    #pragma unroll
    for (int kk = 0; kk < 3; kk++) {
        ah0[kk] = ldh(h16 + (rowbase + lmod) * 96 + kk * 32 + ldiv * 8);
        ah1[kk] = ldh(h16 + (rowbase + 16 + lmod) * 96 + kk * 32 + ldiv * 8);
    }

    f32x4 qa0[6] = {}, qa1[6] = {};
    #pragma unroll
    for (int kk = 0; kk < 3; kk++)
        #pragma unroll
        for (int n = 0; n < 6; n++) {
            f16x8 bf = ldh(wqS + (size_t)(((hd * 6 + n) * 3 + kk) * 64) * 8 + lane * 8);
            qa0[n] = __builtin_amdgcn_mfma_f32_16x16x32_f16(ah0[kk], bf, qa0[n], 0, 0, 0);
            qa1[n] = __builtin_amdgcn_mfma_f32_16x16x32_f16(ah1[kk], bf, qa1[n], 0, 0, 0);
        }
    #pragma unroll
    for (int n = 0; n < 6; n++)
        #pragma unroll
        for (int r = 0; r < 4; r++) {
            stg[(ldiv * 4 + r) * 104 + n * 16 + lmod] = f2h(qa0[n][r]);
            stg[(16 + ldiv * 4 + r) * 104 + n * 16 + lmod] = f2h(qa1[n][r]);
        }
    f16x8 aq0[3], aq1[3];
    #pragma unroll
    for (int kk = 0; kk < 3; kk++) {
        aq0[kk] = ldh(&stg[lmod * 104 + kk * 32 + ldiv * 8]);
        aq1[kk] = ldh(&stg[(16 + lmod) * 104 + kk * 32 + ldiv * 8]);
    }

    const us* Kh = Kall + (size_t)hd * NTOT + (size_t)b * 24 * 1536;
    const us* Vh = Vall + (size_t)hd * NTOT + (size_t)b * 36 * 1024;

    // ---- pass 1: row max ----
    f32x4 mx0 = {-1e30f, -1e30f, -1e30f, -1e30f}, mx1 = mx0;
    for (int c = 0; c < 6; c++) {
        f32x4 s0[4] = {}, s1[4] = {};
        SCORE(c, s0, s1)
        #pragma unroll
        for (int nt = 0; nt < 4; nt++)
            #pragma unroll
            for (int r = 0; r < 4; r++) {
                mx0[r] = fmaxf(mx0[r], s0[nt][r]);
                mx1[r] = fmaxf(mx1[r], s1[nt][r]);
            }
    }
    #pragma unroll
    for (int st = 1; st <= 8; st <<= 1)
        #pragma unroll
        for (int r = 0; r < 4; r++) {
            mx0[r] = fmaxf(mx0[r], __shfl_xor(mx0[r], st));
            mx1[r] = fmaxf(mx1[r], __shfl_xor(mx1[r], st));
        }

    // ---- pass 2: pipelined (score(c+1) between P-write(c) and PV-read(c)) ----
    f32x4 oacc0[6] = {}, oacc1[6] = {};
    f32x4 l0v = {}, l1v = {};
    {
        f32x4 s0[4] = {}, s1[4] = {};
        SCORE(0, s0, s1)
        EXPSTORE(s0, s1, stg)  // chunk 0 -> buffer A
    }
    for (int c = 0; c < 6; c++) {
        f32x4 t0[4] = {}, t1[4] = {};
        if (c < 5) {
            SCORE(c + 1, t0, t1)
        }
        us* rb = (c & 1) ? bufB : stg;
        PVSTEP(c, rb)
        if (c < 5) {
            us* wb = (c & 1) ? stg : bufB;
            EXPSTORE(t0, t1, wb)
        }
    }
    #pragma unroll
    for (int st = 1; st <= 8; st <<= 1)
        #pragma unroll
        for (int r = 0; r < 4; r++) {
            l0v[r] += __shfl_xor(l0v[r], st);
            l1v[r] += __shfl_xor(l1v[r], st);
        }

    us* xp = xpart + (size_t)hd * NTOT;
    #pragma unroll
    for (int r = 0; r < 4; r++) {
        float inv0 = 1.f / l0v[r];
        float inv1 = 1.f / l1v[r];
        #pragma unroll
        for (int n = 0; n < 6; n++) {
            xp[(rowbase + ldiv * 4 + r) * 96 + n * 16 + lmod] = f2h(oacc0[n][r] * inv0);
            xp[(rowbase + 16 + ldiv * 4 + r) * 96 + n * 16 + lmod] = f2h(oacc1[n][r] * inv1);
        }
    }
}

// ---------------- fused head-reduce + LN + FFN ----------------
__global__ void ffn_ln(const float* __restrict__ x, const us* __restrict__ xpart,
                       const float* __restrict__ gln, const float* __restrict__ bln,
                       const us* __restrict__ w1T, const float* __restrict__ b1,
                       const us* __restrict__ w2Tp, const float* __restrict__ b2,
                       float* __restrict__ out) {
    __shared__ float xf[64 * 96];
    __shared__ us lnb[64 * 104];
    __shared__ us mid[64 * 72];
    int tid = threadIdx.x, wave = tid >> 6, lane = tid & 63;
    int lmod = lane & 15, ldiv = lane >> 4, m0 = wave * 16;
    int row0 = blockIdx.x * 64;

    for (int i = wave; i < 64; i += 4) {
        size_t ro = (size_t)(row0 + i) * 96;
        float v0 = x[ro + lane];
        float v1 = (lane < 32) ? x[ro + 64 + lane] : 0.f;
        #pragma unroll
        for (int h = 0; h < H; h++) {
            const us* xp = xpart + (size_t)h * NTOT + ro;
            v0 += (float)__builtin_bit_cast(_Float16, xp[lane]);
            if (lane < 32) v1 += (float)__builtin_bit_cast(_Float16, xp[64 + lane]);
        }
        xf[i * 96 + lane] = v0;
        if (lane < 32) xf[i * 96 + 64 + lane] = v1;
        float sm = v0 + v1, q = v0 * v0 + v1 * v1;
        for (int off = 32; off > 0; off >>= 1) {
            sm += __shfl_xor(sm, off);
            q += __shfl_xor(q, off);
        }
        float mean = sm * (1.0f / D);
        float var = q * (1.0f / D) - mean * mean;
        float rstd = rsqrtf(var + 1e-5f);
        lnb[i * 104 + lane] = f2h((v0 - mean) * rstd * gln[lane] + bln[lane]);
        if (lane < 32)
            lnb[i * 104 + 64 + lane] = f2h((v1 - mean) * rstd * gln[lane + 64] + bln[lane + 64]);
    }
    __syncthreads();

    f32x4 a3[3] = {};
    #pragma unroll
    for (int kk = 0; kk < 3; kk++) {
        f16x8 af = ldh(&lnb[(m0 + lmod) * 104 + kk * 32 + ldiv * 8]);
        #pragma unroll
        for (int n = 0; n < 3; n++) {
            f16x8 bf = ldh(w1T + (size_t)(n * 16 + lmod) * 96 + kk * 32 + ldiv * 8);
            a3[n] = __builtin_amdgcn_mfma_f32_16x16x32_f16(af, bf, a3[n], 0, 0, 0);
        }
    }
    #pragma unroll
    for (int n = 0; n < 3; n++) {
        float bv = b1[n * 16 + lmod];
        #pragma unroll
        for (int r = 0; r < 4; r++) {
            float v = a3[n][r] + bv;
            mid[(m0 + ldiv * 4 + r) * 72 + n * 16 + lmod] = f2h(1.f / (1.f + __expf(-v)));
        }
    }
    #pragma unroll
    for (int r = 0; r < 4; r++) mid[(m0 + ldiv * 4 + r) * 72 + 48 + lmod] = 0;
    __syncthreads();

    f32x4 a6[6] = {};
    #pragma unroll
    for (int kk = 0; kk < 2; kk++) {
        f16x8 af = ldh(&mid[(m0 + lmod) * 72 + kk * 32 + ldiv * 8]);
        #pragma unroll
        for (int n = 0; n < 6; n++) {
            f16x8 bf = ldh(w2Tp + (size_t)(n * 16 + lmod) * 64 + kk * 32 + ldiv * 8);
            a6[n] = __builtin_amdgcn_mfma_f32_16x16x32_f16(af, bf, a6[n], 0, 0, 0);
        }
    }
    #pragma unroll
    for (int n = 0; n < 6; n++) {
        int o = n * 16 + lmod;
        float bv = b2[o];
        #pragma unroll
        for (int r = 0; r < 4; r++) {
            int sr = m0 + ldiv * 4 + r;
            out[(size_t)(row0 + sr) * 96 + o] = xf[sr * 96 + o] + a6[n][r] + bv;
        }
    }
}

extern "C" void kernel_launch(void* const* d_in, const int* in_sizes, int n_in,
                              void* d_out, int out_size, void* d_ws, size_t ws_size,
                              hipStream_t stream) {
    const float* in   = (const float*)d_in[0];
    const float* cdw  = (const float*)d_in[2];
    const float* cdwb = (const float*)d_in[3];
    const float* cpw  = (const float*)d_in[4];
    const float* cpwb = (const float*)d_in[5];
    const float* WQ   = (const float*)d_in[6];
    const float* WK   = (const float*)d_in[7];
    const float* WV   = (const float*)d_in[8];
    const float* WO   = (const float*)d_in[9];
    const float* w1   = (const float*)d_in[10];
    const float* b1   = (const float*)d_in[11];
    const float* w2   = (const float*)d_in[12];
    const float* b2   = (const float*)d_in[13];
    const float* lng  = (const float*)d_in[14];
    const float* lnb  = (const float*)d_in[15];
    float* out = (float*)d_out;
    float* ws = (float*)d_ws;

    float* xA  = ws;
    float* xB  = xA + NTOT;
    float* pe  = xB + NTOT;
    us* lnA    = (us*)(pe + S * D);
    us* lnB    = lnA + NTOT;
    us* Kall   = lnB + NTOT;               // [H][B][24][3][64][8]
    us* Vall   = Kall + (size_t)H * NTOT;  // [H][B][6][6][2][64][8]
    us* xpart  = Vall + (size_t)H * NTOT;  // [H][ROWS][96]
    us* wqS    = xpart + (size_t)H * NTOT;
    us* wkT    = wqS + H * D * D;
    us* wvoT   = wkT + H * D * D;
    us* pw16   = wvoT + H * D * D;
    us* w1T    = pw16 + L * D * D;
    us* w2Tp   = w1T + 48 * 96;
    // total ~= 170 MB (< 256 MB ws)

    pe_kernel<<<(S * D + 255) / 256, 256, 0, stream>>>(pe);
    prep_w<<<(H * D * D + 255) / 256, 256, 0, stream>>>(WQ, WK, cpw, w1, w2,
                                                        wqS, wkT, pw16, w1T, w2Tp);
    prep_wvo<<<H * 6, 256, 0, stream>>>(WV, WO, wvoT);

    conv0f<<<ROWS / 64, 256, 0, stream>>>(in, pe, lng, lnb, xA, lnB,
                                          cdw, cdwb, pw16, cpwb, lng + D, lnb + D);
    conv2<<<ROWS / 64, 256, 0, stream>>>(xA, lnB, xB, lnA, cdw + D * KW, cdwb + D,
                                         pw16 + D * D, cpwb + D, lng + 2 * D, lnb + 2 * D);
    conv2<<<ROWS / 64, 256, 0, stream>>>(xB, lnA, xA, lnB, cdw + 2 * D * KW, cdwb + 2 * D,
                                         pw16 + 2 * D * D, cpwb + 2 * D, lng + 3 * D,
                                         lnb + 3 * D);
    conv3p<<<ROWS / 64, 256, 0, stream>>>(xA, lnB, xB, lnA, cdw + 3 * D * KW, cdwb + 3 * D,
                                          pw16 + 3 * D * D, cpwb + 3 * D, lng + 4 * D,
                                          lnb + 4 * D, wkT, wvoT, Kall, Vall);

    // lnA == h16, xB == x4
    attn_2p4<<<1536, 256, 0, stream>>>(lnA, wqS, Kall, Vall, xpart);

    ffn_ln<<<ROWS / 64, 256, 0, stream>>>(xB, xpart, lng + 5 * D, lnb + 5 * D,
                                          w1T, b1, w2Tp, b2, out);
}

// Round 16
// 336.175 us; speedup vs baseline: 1.0049x; 1.0049x over previous
//
#include <hip/hip_runtime.h>
#include <math.h>

// EmbeddingEncoder: B=128, S=384, D=96, H=4, K=7, L=4.
// Round 16: 48 q-rows per attention wave (3 m-tiles) -> 1.5x fewer B-fragment
// loads (the identified L1-issue bottleneck). Two-pass softmax, no barriers,
// 4 independent waves/block, launch_bounds(256,2). Rest = round 14 (334 us).

constexpr int B = 128;
constexpr int S = 384;
constexpr int D = 96;
constexpr int H = 4;
constexpr int KW = 7;
constexpr int L = 4;
constexpr int ROWS = B * S;                      // 49152
constexpr long long NTOT = (long long)ROWS * D;  // 4718592
constexpr float SQRTD = 9.797958971132712f;

typedef _Float16 f16x8 __attribute__((ext_vector_type(8)));
typedef float f32x4 __attribute__((ext_vector_type(4)));
typedef unsigned short us;
typedef unsigned short us8 __attribute__((ext_vector_type(8)));

__device__ __forceinline__ us f2h(float f) {
    _Float16 h = (_Float16)f;
    return __builtin_bit_cast(us, h);
}
__device__ __forceinline__ f16x8 ldh(const us* p) {
    return *reinterpret_cast<const f16x8*>(p);
}

// ---------------- positional encoding ----------------
__global__ void pe_kernel(float* __restrict__ pe) {
    int idx = blockIdx.x * 256 + threadIdx.x;
    if (idx >= S * D) return;
    int s = idx / D, c = idx - s * D;
    int j = c >> 1;
    float expo = (c & 1) ? (4.0f * j + 2.0f) / 96.0f : (4.0f * j) / 96.0f;
    float freq = expf(-expo * logf(10000.0f));
    float ang = (float)s * freq;
    pe[idx] = (c & 1) ? cosf(ang) : sinf(ang);
}

// ---------------- weight prep ----------------
__global__ void prep_w(const float* __restrict__ WQ, const float* __restrict__ WK,
                       const float* __restrict__ cpw, const float* __restrict__ w1,
                       const float* __restrict__ w2,
                       us* __restrict__ wqS, us* __restrict__ wkT, us* __restrict__ pw16,
                       us* __restrict__ w1T, us* __restrict__ w2Tp) {
    int idx = blockIdx.x * 256 + threadIdx.x;
    if (idx >= H * D * D) return;  // 36864
    int h = idx / (D * D), rem = idx - h * (D * D);
    int d = rem / D, e = rem - d * D;
    int n = e >> 4, lmod = e & 15, kk = d >> 5, ldiv = (d >> 3) & 3, j = d & 7;
    wqS[(size_t)(((h * 6 + n) * 3 + kk) * 64 + ldiv * 16 + lmod) * 8 + j] = f2h(WQ[idx] * SQRTD);
    wkT[(size_t)h * D * D + e * D + d] = f2h(WK[idx]);
    pw16[idx] = f2h(cpw[idx]);  // L*D*D == 36864
    if (idx < 48 * 96) {
        int m = idx / 96, c = idx - m * 96;
        w1T[idx] = f2h(w1[c * 48 + m]);
    }
    if (idx < 96 * 64) {
        int o = idx / 64, m = idx - o * 64;
        w2Tp[idx] = (m < 48) ? f2h(w2[m * 96 + o]) : (us)0;
    }
}

// ---------------- WVO_h = WV_h @ WO_h, stored transposed [h][o][d] ----------------
__global__ void prep_wvo(const float* __restrict__ WV, const float* __restrict__ WO,
                         us* __restrict__ wvoT) {
    int blk = blockIdx.x;  // 24 = H * 6
    int h = blk / 6, ot = blk - h * 6;
    int tid = threadIdx.x;
    const float* wv = WV + (size_t)h * D * D;
    const float* wo = WO + (size_t)h * D * D;
    for (int i = tid; i < 16 * 96; i += 256) {
        int o = ot * 16 + i / 96, d = i - (i / 96) * 96;
        float acc = 0.f;
        for (int e = 0; e < 96; e++) acc += wv[d * 96 + e] * wo[e * 96 + o];
        wvoT[(size_t)h * D * D + o * 96 + d] = f2h(acc);
    }
}

// ---------------- conv0: embed + LN0 (halo inline) + dw + pw + residual + LN1 ----------------
__global__ void conv0f(const float* __restrict__ in, const float* __restrict__ pe,
                       const float* __restrict__ g0, const float* __restrict__ b0,
                       float* __restrict__ xout, us* __restrict__ lnout,
                       const float* __restrict__ dwW, const float* __restrict__ dwB,
                       const us* __restrict__ pwW, const float* __restrict__ pwb,
                       const float* __restrict__ gnext, const float* __restrict__ bnext) {
    __shared__ us lnb_s[70 * 104];
    __shared__ us dwb_s[64 * 104];
    __shared__ float lw[96 * 8];
    int tid = threadIdx.x;
    int wave = tid >> 6, lane = tid & 63;
    int r0 = blockIdx.x * 64;
    int b = r0 / S, s0 = r0 % S;

    for (int i = tid; i < 96 * KW; i += 256) lw[(i / KW) * 8 + (i % KW)] = dwW[i];

    for (int i = wave; i < 70; i += 4) {
        int s = s0 - 3 + i;
        bool valid = (unsigned)s < (unsigned)S;
        float v0 = 0.f, v1 = 0.f;
        if (valid) {
            size_t ro = ((size_t)b * S + s) * 96;
            v0 = in[ro + lane] * SQRTD + pe[s * 96 + lane];
            v1 = (lane < 32) ? in[ro + 64 + lane] * SQRTD + pe[s * 96 + 64 + lane] : 0.f;
        }
        float sm = v0 + v1, q = v0 * v0 + v1 * v1;
        for (int off = 32; off > 0; off >>= 1) {
            sm += __shfl_xor(sm, off);
            q += __shfl_xor(q, off);
        }
        float mean = sm * (1.0f / D);
        float var = q * (1.0f / D) - mean * mean;
        float rstd = rsqrtf(var + 1e-5f);
        lnb_s[i * 104 + lane] = f2h(valid ? (v0 - mean) * rstd * g0[lane] + b0[lane] : 0.f);
        if (lane < 32)
            lnb_s[i * 104 + 64 + lane] =
                f2h(valid ? (v1 - mean) * rstd * g0[lane + 64] + b0[lane + 64] : 0.f);
    }
    __syncthreads();

    for (int u = tid; u < 768; u += 256) {
        int j = u / 12, c0 = (u - (u / 12) * 12) * 8;
        float acc[8];
        #pragma unroll
        for (int j2 = 0; j2 < 8; j2++) acc[j2] = dwB[c0 + j2];
        #pragma unroll
        for (int k = 0; k < KW; k++) {
            f16x8 v = ldh(&lnb_s[(j + k) * 104 + c0]);
            #pragma unroll
            for (int j2 = 0; j2 < 8; j2++) acc[j2] += (float)v[j2] * lw[(c0 + j2) * 8 + k];
        }
        us8 o;
        #pragma unroll
        for (int j2 = 0; j2 < 8; j2++) o[j2] = f2h(acc[j2]);
        *reinterpret_cast<us8*>(&dwb_s[j * 104 + c0]) = o;
    }
    __syncthreads();

    int lmod = lane & 15, ldiv = lane >> 4, m0 = wave * 16;
    f32x4 acc[6] = {};
    #pragma unroll
    for (int kk = 0; kk < 3; kk++) {
        f16x8 af = ldh(&dwb_s[(m0 + lmod) * 104 + kk * 32 + ldiv * 8]);
        #pragma unroll
        for (int n = 0; n < 6; n++) {
            f16x8 bf = ldh(pwW + (size_t)(n * 16 + lmod) * 96 + kk * 32 + ldiv * 8);
            acc[n] = __builtin_amdgcn_mfma_f32_16x16x32_f16(af, bf, acc[n], 0, 0, 0);
        }
    }

    float gv[6], bv2[6], pb[6];
    #pragma unroll
    for (int n = 0; n < 6; n++) {
        int o = n * 16 + lmod;
        gv[n] = gnext[o];
        bv2[n] = bnext[o];
        pb[n] = pwb[o];
    }
    #pragma unroll
    for (int n = 0; n < 6; n++) {
        int o = n * 16 + lmod;
        #pragma unroll
        for (int r = 0; r < 4; r++) {
            int sr = m0 + ldiv * 4 + r;
            size_t row = (size_t)r0 + sr;
            float base = in[row * 96 + o] * SQRTD + pe[(s0 + sr) * 96 + o];
            acc[n][r] = base + fmaxf(acc[n][r] + pb[n], 0.f);
        }
    }
    #pragma unroll
    for (int r = 0; r < 4; r++) {
        float sm = 0.f, qq = 0.f;
        #pragma unroll
        for (int n = 0; n < 6; n++) {
            sm += acc[n][r];
            qq += acc[n][r] * acc[n][r];
        }
        #pragma unroll
        for (int st = 1; st <= 8; st <<= 1) {
            sm += __shfl_xor(sm, st);
            qq += __shfl_xor(qq, st);
        }
        float mean = sm * (1.0f / D);
        float var = qq * (1.0f / D) - mean * mean;
        float rstd = rsqrtf(var + 1e-5f);
        size_t row = (size_t)r0 + m0 + ldiv * 4 + r;
        #pragma unroll
        for (int n = 0; n < 6; n++) {
            int o = n * 16 + lmod;
            xout[row * 96 + o] = acc[n][r];
            lnout[row * 96 + o] = f2h((acc[n][r] - mean) * rstd * gv[n] + bv2[n]);
        }
    }
}

// ---------------- mid conv layer: dw(lnin global f16) -> pw -> residual -> LN_next ----------------
__global__ void conv2(const float* __restrict__ xin, const us* __restrict__ lnin,
                      float* __restrict__ xout, us* __restrict__ lnout,
                      const float* __restrict__ dwW, const float* __restrict__ dwB,
                      const us* __restrict__ pwW, const float* __restrict__ pwb,
                      const float* __restrict__ gnext, const float* __restrict__ bnext) {
    __shared__ us dwb_s[64 * 104];
    __shared__ float lw[96 * 8];
    int tid = threadIdx.x;
    int wave = tid >> 6, lane = tid & 63;
    int r0 = blockIdx.x * 64;
    int b = r0 / S, s0 = r0 % S;

    for (int i = tid; i < 96 * KW; i += 256) lw[(i / KW) * 8 + (i % KW)] = dwW[i];
    __syncthreads();

    for (int u = tid; u < 768; u += 256) {
        int j = u / 12, c0 = (u - (u / 12) * 12) * 8;
        float acc[8];
        #pragma unroll
        for (int j2 = 0; j2 < 8; j2++) acc[j2] = dwB[c0 + j2];
        #pragma unroll
        for (int k = 0; k < KW; k++) {
            int ss = s0 + j + k - 3;
            if ((unsigned)ss < (unsigned)S) {
                f16x8 v = ldh(lnin + ((size_t)b * S + ss) * 96 + c0);
                #pragma unroll
                for (int j2 = 0; j2 < 8; j2++) acc[j2] += (float)v[j2] * lw[(c0 + j2) * 8 + k];
            }
        }
        us8 o;
        #pragma unroll
        for (int j2 = 0; j2 < 8; j2++) o[j2] = f2h(acc[j2]);
        *reinterpret_cast<us8*>(&dwb_s[j * 104 + c0]) = o;
    }
    __syncthreads();

    int lmod = lane & 15, ldiv = lane >> 4, m0 = wave * 16;
    f32x4 acc[6] = {};
    #pragma unroll
    for (int kk = 0; kk < 3; kk++) {
        f16x8 af = ldh(&dwb_s[(m0 + lmod) * 104 + kk * 32 + ldiv * 8]);
        #pragma unroll
        for (int n = 0; n < 6; n++) {
            f16x8 bf = ldh(pwW + (size_t)(n * 16 + lmod) * 96 + kk * 32 + ldiv * 8);
            acc[n] = __builtin_amdgcn_mfma_f32_16x16x32_f16(af, bf, acc[n], 0, 0, 0);
        }
    }

    float gv[6], bv2[6], pb[6];
    #pragma unroll
    for (int n = 0; n < 6; n++) {
        int o = n * 16 + lmod;
        gv[n] = gnext[o];
        bv2[n] = bnext[o];
        pb[n] = pwb[o];
    }
    #pragma unroll
    for (int n = 0; n < 6; n++) {
        #pragma unroll
        for (int r = 0; r < 4; r++) {
            size_t row = (size_t)r0 + m0 + ldiv * 4 + r;
            acc[n][r] = xin[row * 96 + n * 16 + lmod] + fmaxf(acc[n][r] + pb[n], 0.f);
        }
    }
    #pragma unroll
    for (int r = 0; r < 4; r++) {
        float sm = 0.f, qq = 0.f;
        #pragma unroll
        for (int n = 0; n < 6; n++) {
            sm += acc[n][r];
            qq += acc[n][r] * acc[n][r];
        }
        #pragma unroll
        for (int st = 1; st <= 8; st <<= 1) {
            sm += __shfl_xor(sm, st);
            qq += __shfl_xor(qq, st);
        }
        float mean = sm * (1.0f / D);
        float var = qq * (1.0f / D) - mean * mean;
        float rstd = rsqrtf(var + 1e-5f);
        size_t row = (size_t)r0 + m0 + ldiv * 4 + r;
        #pragma unroll
        for (int n = 0; n < 6; n++) {
            int o = n * 16 + lmod;
            xout[row * 96 + o] = acc[n][r];
            lnout[row * 96 + o] = f2h((acc[n][r] - mean) * rstd * gv[n] + bv2[n]);
        }
    }
}

// ---------------- conv3 + K/V' projection fused ----------------
__global__ void conv3p(const float* __restrict__ xin, const us* __restrict__ lnin,
                       float* __restrict__ xout, us* __restrict__ lnout,
                       const float* __restrict__ dwW, const float* __restrict__ dwB,
                       const us* __restrict__ pwW, const float* __restrict__ pwb,
                       const float* __restrict__ gnext, const float* __restrict__ bnext,
                       const us* __restrict__ wkT, const us* __restrict__ wvoT,
                       us* __restrict__ Kall, us* __restrict__ Vall) {
    __shared__ float lw[96 * 8];
    __shared__ us stg[96 * 72];     // union: dw buffer [64][104] / proj staging
    __shared__ us lnstg[64 * 104];  // LN'd rows (h16) for proj A-frags
    int tid = threadIdx.x;
    int wave = tid >> 6, lane = tid & 63;
    int lmod = lane & 15, ldiv = lane >> 4, m0 = wave * 16;
    int r0 = blockIdx.x * 64;
    int b = r0 / S, s0 = r0 % S;

    for (int i = tid; i < 96 * KW; i += 256) lw[(i / KW) * 8 + (i % KW)] = dwW[i];
    __syncthreads();

    for (int u = tid; u < 768; u += 256) {
        int j = u / 12, c0 = (u - (u / 12) * 12) * 8;
        float acc[8];
        #pragma unroll
        for (int j2 = 0; j2 < 8; j2++) acc[j2] = dwB[c0 + j2];
        #pragma unroll
        for (int k = 0; k < KW; k++) {
            int ss = s0 + j + k - 3;
            if ((unsigned)ss < (unsigned)S) {
                f16x8 v = ldh(lnin + ((size_t)b * S + ss) * 96 + c0);
                #pragma unroll
                for (int j2 = 0; j2 < 8; j2++) acc[j2] += (float)v[j2] * lw[(c0 + j2) * 8 + k];
            }
        }
        us8 o;
        #pragma unroll
        for (int j2 = 0; j2 < 8; j2++) o[j2] = f2h(acc[j2]);
        *reinterpret_cast<us8*>(&stg[j * 104 + c0]) = o;
    }
    __syncthreads();

    f32x4 acc[6] = {};
    #pragma unroll
    for (int kk = 0; kk < 3; kk++) {
        f16x8 af = ldh(&stg[(m0 + lmod) * 104 + kk * 32 + ldiv * 8]);
        #pragma unroll
        for (int n = 0; n < 6; n++) {
            f16x8 bf = ldh(pwW + (size_t)(n * 16 + lmod) * 96 + kk * 32 + ldiv * 8);
            acc[n] = __builtin_amdgcn_mfma_f32_16x16x32_f16(af, bf, acc[n], 0, 0, 0);
        }
    }

    float gv[6], bv2[6], pb[6];
    #pragma unroll
    for (int n = 0; n < 6; n++) {
        int o = n * 16 + lmod;
        gv[n] = gnext[o];
        bv2[n] = bnext[o];
        pb[n] = pwb[o];
    }
    #pragma unroll
    for (int n = 0; n < 6; n++) {
        #pragma unroll
        for (int r = 0; r < 4; r++) {
            size_t row = (size_t)r0 + m0 + ldiv * 4 + r;
            acc[n][r] = xin[row * 96 + n * 16 + lmod] + fmaxf(acc[n][r] + pb[n], 0.f);
        }
    }
    #pragma unroll
    for (int r = 0; r < 4; r++) {
        float sm = 0.f, qq = 0.f;
        #pragma unroll
        for (int n = 0; n < 6; n++) {
            sm += acc[n][r];
            qq += acc[n][r] * acc[n][r];
        }
        #pragma unroll
        for (int st = 1; st <= 8; st <<= 1) {
            sm += __shfl_xor(sm, st);
            qq += __shfl_xor(qq, st);
        }
        float mean = sm * (1.0f / D);
        float var = qq * (1.0f / D) - mean * mean;
        float rstd = rsqrtf(var + 1e-5f);
        size_t row = (size_t)r0 + m0 + ldiv * 4 + r;
        #pragma unroll
        for (int n = 0; n < 6; n++) {
            int o = n * 16 + lmod;
            xout[row * 96 + o] = acc[n][r];
            us hv = f2h((acc[n][r] - mean) * rstd * gv[n] + bv2[n]);
            lnout[row * 96 + o] = hv;
            lnstg[(m0 + ldiv * 4 + r) * 104 + o] = hv;
        }
    }
    __syncthreads();

    f16x8 af[3];
    #pragma unroll
    for (int kk = 0; kk < 3; kk++)
        af[kk] = ldh(&lnstg[(m0 + lmod) * 104 + kk * 32 + ldiv * 8]);

    for (int hd = 0; hd < H; hd++) {
        // ---- K ----
        f32x4 ka[6] = {};
        #pragma unroll
        for (int kk = 0; kk < 3; kk++)
            #pragma unroll
            for (int n = 0; n < 6; n++) {
                f16x8 bf =
                    ldh(wkT + (size_t)hd * D * D + (size_t)(n * 16 + lmod) * 96 + kk * 32 + ldiv * 8);
                ka[n] = __builtin_amdgcn_mfma_f32_16x16x32_f16(af[kk], bf, ka[n], 0, 0, 0);
            }
        __syncthreads();
        us* kT = stg + wave * 1664;
        #pragma unroll
        for (int n = 0; n < 6; n++)
            #pragma unroll
            for (int r = 0; r < 4; r++)
                kT[(ldiv * 4 + r) * 104 + n * 16 + lmod] = f2h(ka[n][r]);
        int t0 = (r0 % S) / 16 + wave;
        us* dst = Kall + (size_t)hd * NTOT + ((size_t)(b * 24 + t0) * 3) * 512;
        #pragma unroll
        for (int kk = 0; kk < 3; kk++) {
            us8 v = *reinterpret_cast<const us8*>(&kT[lmod * 104 + kk * 32 + ldiv * 8]);
            *reinterpret_cast<us8*>(dst + kk * 512 + lane * 8) = v;
        }
        // ---- V' ----
        f32x4 va[6] = {};
        #pragma unroll
        for (int kk = 0; kk < 3; kk++)
            #pragma unroll
            for (int n = 0; n < 6; n++) {
                f16x8 bf = ldh(wvoT + (size_t)hd * D * D + (size_t)(n * 16 + lmod) * 96 + kk * 32 +
                               ldiv * 8);
                va[n] = __builtin_amdgcn_mfma_f32_16x16x32_f16(af[kk], bf, va[n], 0, 0, 0);
            }
        __syncthreads();
        #pragma unroll
        for (int n = 0; n < 6; n++)
            #pragma unroll
            for (int r = 0; r < 4; r++)
                stg[(n * 16 + lmod) * 72 + m0 + ldiv * 4 + r] = f2h(va[n][r]);
        __syncthreads();
        int cblk = (r0 % S) / 64;
        us* dsth = Vall + (size_t)hd * NTOT;
        #pragma unroll
        for (int n = 0; n < 6; n++)
            #pragma unroll
            for (int kk = 0; kk < 2; kk++) {
                us8 v =
                    *reinterpret_cast<const us8*>(&stg[(n * 16 + lmod) * 72 + kk * 32 + ldiv * 8]);
                *reinterpret_cast<us8*>(
                    dsth + ((size_t)((b * 6 + n) * 6 + cblk) * 2 + kk) * 512 + lane * 8) = v;
            }
    }
}

// ---------------- two-pass attention, 48 q-rows per wave (3 m-tiles) ----------------
// grid 1024 x 256 threads; 4 independent waves/block, no barriers.
__global__ __launch_bounds__(256, 2) void attn_3m(const us* __restrict__ h16,
                                                  const us* __restrict__ wqS,
                                                  const us* __restrict__ Kall,
                                                  const us* __restrict__ Vall,
                                                  us* __restrict__ xpart) {
    __shared__ us stg4[4][48 * 104];  // per-wave: Q staging (stride 104), then P (stride 72)
    int tid = threadIdx.x, wave = tid >> 6, lane = tid & 63;
    us* stg = stg4[wave];
    int lmod = lane & 15, ldiv = lane >> 4;
    int p = blockIdx.x;
    int gl = (((p & 7) * 128 + (p >> 3)) << 2) + wave;  // 1024 = 8*128, XCD-chunked
    int t = gl & 7;
    int bh = gl >> 3;
    int b = bh >> 2, hd = bh & 3;
    size_t rowbase = (size_t)b * S + t * 48;

    // Q projection for 3 m-tiles (wq B-frag loaded once, used 3x)
    f32x4 qa0[6] = {}, qa1[6] = {}, qa2[6] = {};
    #pragma unroll
    for (int kk = 0; kk < 3; kk++) {
        f16x8 a0 = ldh(h16 + (rowbase + lmod) * 96 + kk * 32 + ldiv * 8);
        f16x8 a1 = ldh(h16 + (rowbase + 16 + lmod) * 96 + kk * 32 + ldiv * 8);
        f16x8 a2 = ldh(h16 + (rowbase + 32 + lmod) * 96 + kk * 32 + ldiv * 8);
        #pragma unroll
        for (int n = 0; n < 6; n++) {
            f16x8 bf = ldh(wqS + (size_t)(((hd * 6 + n) * 3 + kk) * 64) * 8 + lane * 8);
            qa0[n] = __builtin_amdgcn_mfma_f32_16x16x32_f16(a0, bf, qa0[n], 0, 0, 0);
            qa1[n] = __builtin_amdgcn_mfma_f32_16x16x32_f16(a1, bf, qa1[n], 0, 0, 0);
            qa2[n] = __builtin_amdgcn_mfma_f32_16x16x32_f16(a2, bf, qa2[n], 0, 0, 0);
        }
    }
    #pragma unroll
    for (int n = 0; n < 6; n++)
        #pragma unroll
        for (int r = 0; r < 4; r++) {
            stg[(ldiv * 4 + r) * 104 + n * 16 + lmod] = f2h(qa0[n][r]);
            stg[(16 + ldiv * 4 + r) * 104 + n * 16 + lmod] = f2h(qa1[n][r]);
            stg[(32 + ldiv * 4 + r) * 104 + n * 16 + lmod] = f2h(qa2[n][r]);
        }
    f16x8 aq0[3], aq1[3], aq2[3];
    #pragma unroll
    for (int kk = 0; kk < 3; kk++) {
        aq0[kk] = ldh(&stg[lmod * 104 + kk * 32 + ldiv * 8]);
        aq1[kk] = ldh(&stg[(16 + lmod) * 104 + kk * 32 + ldiv * 8]);
        aq2[kk] = ldh(&stg[(32 + lmod) * 104 + kk * 32 + ldiv * 8]);
    }

    const us* Kh = Kall + (size_t)hd * NTOT + (size_t)b * 24 * 1536;
    const us* Vh = Vall + (size_t)hd * NTOT + (size_t)b * 36 * 1024;

    // ---- pass 1: row max ----
    f32x4 mx0 = {-1e30f, -1e30f, -1e30f, -1e30f}, mx1 = mx0, mx2 = mx0;
    for (int c = 0; c < 6; c++) {
        f32x4 s0[4] = {}, s1[4] = {}, s2[4] = {};
        __builtin_amdgcn_s_setprio(1);
        #pragma unroll
        for (int nt = 0; nt < 4; nt++)
            #pragma unroll
            for (int kk = 0; kk < 3; kk++) {
                f16x8 bf = ldh(Kh + (size_t)((c * 4 + nt) * 3 + kk) * 512 + lane * 8);
                s0[nt] = __builtin_amdgcn_mfma_f32_16x16x32_f16(aq0[kk], bf, s0[nt], 0, 0, 0);
                s1[nt] = __builtin_amdgcn_mfma_f32_16x16x32_f16(aq1[kk], bf, s1[nt], 0, 0, 0);
                s2[nt] = __builtin_amdgcn_mfma_f32_16x16x32_f16(aq2[kk], bf, s2[nt], 0, 0, 0);
            }
        __builtin_amdgcn_s_setprio(0);
        #pragma unroll
        for (int nt = 0; nt < 4; nt++)
            #pragma unroll
            for (int r = 0; r < 4; r++) {
                mx0[r] = fmaxf(mx0[r], s0[nt][r]);
                mx1[r] = fmaxf(mx1[r], s1[nt][r]);
                mx2[r] = fmaxf(mx2[r], s2[nt][r]);
            }
    }
    #pragma unroll
    for (int st = 1; st <= 8; st <<= 1)
        #pragma unroll
        for (int r = 0; r < 4; r++) {
            mx0[r] = fmaxf(mx0[r], __shfl_xor(mx0[r], st));
            mx1[r] = fmaxf(mx1[r], __shfl_xor(mx1[r], st));
            mx2[r] = fmaxf(mx2[r], __shfl_xor(mx2[r], st));
        }

    // ---- pass 2: recompute scores, exp, l, PV ----
    f32x4 oacc0[6] = {}, oacc1[6] = {}, oacc2[6] = {};
    f32x4 l0v = {}, l1v = {}, l2v = {};
    for (int c = 0; c < 6; c++) {
        f32x4 s0[4] = {}, s1[4] = {}, s2[4] = {};
        __builtin_amdgcn_s_setprio(1);
        #pragma unroll
        for (int nt = 0; nt < 4; nt++)
            #pragma unroll
            for (int kk = 0; kk < 3; kk++) {
                f16x8 bf = ldh(Kh + (size_t)((c * 4 + nt) * 3 + kk) * 512 + lane * 8);
                s0[nt] = __builtin_amdgcn_mfma_f32_16x16x32_f16(aq0[kk], bf, s0[nt], 0, 0, 0);
                s1[nt] = __builtin_amdgcn_mfma_f32_16x16x32_f16(aq1[kk], bf, s1[nt], 0, 0, 0);
                s2[nt] = __builtin_amdgcn_mfma_f32_16x16x32_f16(aq2[kk], bf, s2[nt], 0, 0, 0);
            }
        __builtin_amdgcn_s_setprio(0);
        #pragma unroll
        for (int nt = 0; nt < 4; nt++)
            #pragma unroll
            for (int r = 0; r < 4; r++) {
                float p0 = __expf(s0[nt][r] - mx0[r]);
                float p1 = __expf(s1[nt][r] - mx1[r]);
                float p2 = __expf(s2[nt][r] - mx2[r]);
                l0v[r] += p0;
                l1v[r] += p1;
                l2v[r] += p2;
                stg[(ldiv * 4 + r) * 72 + nt * 16 + lmod] = f2h(p0);
                stg[(16 + ldiv * 4 + r) * 72 + nt * 16 + lmod] = f2h(p1);
                stg[(32 + ldiv * 4 + r) * 72 + nt * 16 + lmod] = f2h(p2);
            }
        __builtin_amdgcn_s_setprio(1);
        #pragma unroll
        for (int kk = 0; kk < 2; kk++) {
            f16x8 pf0 = ldh(&stg[lmod * 72 + kk * 32 + ldiv * 8]);
            f16x8 pf1 = ldh(&stg[(16 + lmod) * 72 + kk * 32 + ldiv * 8]);
            f16x8 pf2 = ldh(&stg[(32 + lmod) * 72 + kk * 32 + ldiv * 8]);
            #pragma unroll
            for (int n = 0; n < 6; n++) {
                f16x8 bf = ldh(Vh + (size_t)((n * 6 + c) * 2 + kk) * 512 + lane * 8);
                oacc0[n] = __builtin_amdgcn_mfma_f32_16x16x32_f16(pf0, bf, oacc0[n], 0, 0, 0);
                oacc1[n] = __builtin_amdgcn_mfma_f32_16x16x32_f16(pf1, bf, oacc1[n], 0, 0, 0);
                oacc2[n] = __builtin_amdgcn_mfma_f32_16x16x32_f16(pf2, bf, oacc2[n], 0, 0, 0);
            }
        }
        __builtin_amdgcn_s_setprio(0);
    }
    #pragma unroll
    for (int st = 1; st <= 8; st <<= 1)
        #pragma unroll
        for (int r = 0; r < 4; r++) {
            l0v[r] += __shfl_xor(l0v[r], st);
            l1v[r] += __shfl_xor(l1v[r], st);
            l2v[r] += __shfl_xor(l2v[r], st);
        }

    us* xp = xpart + (size_t)hd * NTOT;
    #pragma unroll
    for (int r = 0; r < 4; r++) {
        float inv0 = 1.f / l0v[r];
        float inv1 = 1.f / l1v[r];
        float inv2 = 1.f / l2v[r];
        #pragma unroll
        for (int n = 0; n < 6; n++) {
            xp[(rowbase + ldiv * 4 + r) * 96 + n * 16 + lmod] = f2h(oacc0[n][r] * inv0);
            xp[(rowbase + 16 + ldiv * 4 + r) * 96 + n * 16 + lmod] = f2h(oacc1[n][r] * inv1);
            xp[(rowbase + 32 + ldiv * 4 + r) * 96 + n * 16 + lmod] = f2h(oacc2[n][r] * inv2);
        }
    }
}

// ---------------- fused head-reduce + LN + FFN ----------------
__global__ void ffn_ln(const float* __restrict__ x, const us* __restrict__ xpart,
                       const float* __restrict__ gln, const float* __restrict__ bln,
                       const us* __restrict__ w1T, const float* __restrict__ b1,
                       const us* __restrict__ w2Tp, const float* __restrict__ b2,
                       float* __restrict__ out) {
    __shared__ float xf[64 * 96];
    __shared__ us lnb[64 * 104];
    __shared__ us mid[64 * 72];
    int tid = threadIdx.x, wave = tid >> 6, lane = tid & 63;
    int lmod = lane & 15, ldiv = lane >> 4, m0 = wave * 16;
    int row0 = blockIdx.x * 64;

    for (int i = wave; i < 64; i += 4) {
        size_t ro = (size_t)(row0 + i) * 96;
        float v0 = x[ro + lane];
        float v1 = (lane < 32) ? x[ro + 64 + lane] : 0.f;
        #pragma unroll
        for (int h = 0; h < H; h++) {
            const us* xp = xpart + (size_t)h * NTOT + ro;
            v0 += (float)__builtin_bit_cast(_Float16, xp[lane]);
            if (lane < 32) v1 += (float)__builtin_bit_cast(_Float16, xp[64 + lane]);
        }
        xf[i * 96 + lane] = v0;
        if (lane < 32) xf[i * 96 + 64 + lane] = v1;
        float sm = v0 + v1, q = v0 * v0 + v1 * v1;
        for (int off = 32; off > 0; off >>= 1) {
            sm += __shfl_xor(sm, off);
            q += __shfl_xor(q, off);
        }
        float mean = sm * (1.0f / D);
        float var = q * (1.0f / D) - mean * mean;
        float rstd = rsqrtf(var + 1e-5f);
        lnb[i * 104 + lane] = f2h((v0 - mean) * rstd * gln[lane] + bln[lane]);
        if (lane < 32)
            lnb[i * 104 + 64 + lane] = f2h((v1 - mean) * rstd * gln[lane + 64] + bln[lane + 64]);
    }
    __syncthreads();

    f32x4 a3[3] = {};
    #pragma unroll
    for (int kk = 0; kk < 3; kk++) {
        f16x8 af = ldh(&lnb[(m0 + lmod) * 104 + kk * 32 + ldiv * 8]);
        #pragma unroll
        for (int n = 0; n < 3; n++) {
            f16x8 bf = ldh(w1T + (size_t)(n * 16 + lmod) * 96 + kk * 32 + ldiv * 8);
            a3[n] = __builtin_amdgcn_mfma_f32_16x16x32_f16(af, bf, a3[n], 0, 0, 0);
        }
    }
    #pragma unroll
    for (int n = 0; n < 3; n++) {
        float bv = b1[n * 16 + lmod];
        #pragma unroll
        for (int r = 0; r < 4; r++) {
            float v = a3[n][r] + bv;
            mid[(m0 + ldiv * 4 + r) * 72 + n * 16 + lmod] = f2h(1.f / (1.f + __expf(-v)));
        }
    }
    #pragma unroll
    for (int r = 0; r < 4; r++) mid[(m0 + ldiv * 4 + r) * 72 + 48 + lmod] = 0;
    __syncthreads();

    f32x4 a6[6] = {};
    #pragma unroll
    for (int kk = 0; kk < 2; kk++) {
        f16x8 af = ldh(&mid[(m0 + lmod) * 72 + kk * 32 + ldiv * 8]);
        #pragma unroll
        for (int n = 0; n < 6; n++) {
            f16x8 bf = ldh(w2Tp + (size_t)(n * 16 + lmod) * 64 + kk * 32 + ldiv * 8);
            a6[n] = __builtin_amdgcn_mfma_f32_16x16x32_f16(af, bf, a6[n], 0, 0, 0);
        }
    }
    #pragma unroll
    for (int n = 0; n < 6; n++) {
        int o = n * 16 + lmod;
        float bv = b2[o];
        #pragma unroll
        for (int r = 0; r < 4; r++) {
            int sr = m0 + ldiv * 4 + r;
            out[(size_t)(row0 + sr) * 96 + o] = xf[sr * 96 + o] + a6[n][r] + bv;
        }
    }
}

extern "C" void kernel_launch(void* const* d_in, const int* in_sizes, int n_in,
                              void* d_out, int out_size, void* d_ws, size_t ws_size,
                              hipStream_t stream) {
    const float* in   = (const float*)d_in[0];
    const float* cdw  = (const float*)d_in[2];
    const float* cdwb = (const float*)d_in[3];
    const float* cpw  = (const float*)d_in[4];
    const float* cpwb = (const float*)d_in[5];
    const float* WQ   = (const float*)d_in[6];
    const float* WK   = (const float*)d_in[7];
    const float* WV   = (const float*)d_in[8];
    const float* WO   = (const float*)d_in[9];
    const float* w1   = (const float*)d_in[10];
    const float* b1   = (const float*)d_in[11];
    const float* w2   = (const float*)d_in[12];
    const float* b2   = (const float*)d_in[13];
    const float* lng  = (const float*)d_in[14];
    const float* lnb  = (const float*)d_in[15];
    float* out = (float*)d_out;
    float* ws = (float*)d_ws;

    float* xA  = ws;
    float* xB  = xA + NTOT;
    float* pe  = xB + NTOT;
    us* lnA    = (us*)(pe + S * D);
    us* lnB    = lnA + NTOT;
    us* Kall   = lnB + NTOT;               // [H][B][24][3][64][8]
    us* Vall   = Kall + (size_t)H * NTOT;  // [H][B][6][6][2][64][8]
    us* xpart  = Vall + (size_t)H * NTOT;  // [H][ROWS][96]
    us* wqS    = xpart + (size_t)H * NTOT;
    us* wkT    = wqS + H * D * D;
    us* wvoT   = wkT + H * D * D;
    us* pw16   = wvoT + H * D * D;
    us* w1T    = pw16 + L * D * D;
    us* w2Tp   = w1T + 48 * 96;
    // total ~= 170 MB (< 256 MB ws)

    pe_kernel<<<(S * D + 255) / 256, 256, 0, stream>>>(pe);
    prep_w<<<(H * D * D + 255) / 256, 256, 0, stream>>>(WQ, WK, cpw, w1, w2,
                                                        wqS, wkT, pw16, w1T, w2Tp);
    prep_wvo<<<H * 6, 256, 0, stream>>>(WV, WO, wvoT);

    conv0f<<<ROWS / 64, 256, 0, stream>>>(in, pe, lng, lnb, xA, lnB,
                                          cdw, cdwb, pw16, cpwb, lng + D, lnb + D);
    conv2<<<ROWS / 64, 256, 0, stream>>>(xA, lnB, xB, lnA, cdw + D * KW, cdwb + D,
                                         pw16 + D * D, cpwb + D, lng + 2 * D, lnb + 2 * D);
    conv2<<<ROWS / 64, 256, 0, stream>>>(xB, lnA, xA, lnB, cdw + 2 * D * KW, cdwb + 2 * D,
                                         pw16 + 2 * D * D, cpwb + 2 * D, lng + 3 * D,
                                         lnb + 3 * D);
    conv3p<<<ROWS / 64, 256, 0, stream>>>(xA, lnB, xB, lnA, cdw + 3 * D * KW, cdwb + 3 * D,
                                          pw16 + 3 * D * D, cpwb + 3 * D, lng + 4 * D,
                                          lnb + 4 * D, wkT, wvoT, Kall, Vall);

    // lnA == h16, xB == x4
    attn_3m<<<1024, 256, 0, stream>>>(lnA, wqS, Kall, Vall, xpart);

    ffn_ln<<<ROWS / 64, 256, 0, stream>>>(xB, xpart, lng + 5 * D, lnb + 5 * D,
                                          w1T, b1, w2Tp, b2, out);
}

// Round 17
// 304.537 us; speedup vs baseline: 1.1093x; 1.1039x over previous
//
#include <hip/hip_runtime.h>
#include <math.h>

// EmbeddingEncoder: B=128, S=384, D=96, H=4, K=7, L=4.
// Round 17: block-cooperative LDS-staged attention (GEMM-style): 4 waves share
// (b,head,128 q-rows); K/V double-buffered in LDS via batched cooperative loads
// (1 barrier/chunk); B-frags via ds_read_b128. V global layout chunk-major.

constexpr int B = 128;
constexpr int S = 384;
constexpr int D = 96;
constexpr int H = 4;
constexpr int KW = 7;
constexpr int L = 4;
constexpr int ROWS = B * S;                      // 49152
constexpr long long NTOT = (long long)ROWS * D;  // 4718592
constexpr float SQRTD = 9.797958971132712f;

typedef _Float16 f16x8 __attribute__((ext_vector_type(8)));
typedef float f32x4 __attribute__((ext_vector_type(4)));
typedef unsigned short us;
typedef unsigned short us8 __attribute__((ext_vector_type(8)));

__device__ __forceinline__ us f2h(float f) {
    _Float16 h = (_Float16)f;
    return __builtin_bit_cast(us, h);
}
__device__ __forceinline__ f16x8 ldh(const us* p) {
    return *reinterpret_cast<const f16x8*>(p);
}

// ---------------- positional encoding ----------------
__global__ void pe_kernel(float* __restrict__ pe) {
    int idx = blockIdx.x * 256 + threadIdx.x;
    if (idx >= S * D) return;
    int s = idx / D, c = idx - s * D;
    int j = c >> 1;
    float expo = (c & 1) ? (4.0f * j + 2.0f) / 96.0f : (4.0f * j) / 96.0f;
    float freq = expf(-expo * logf(10000.0f));
    float ang = (float)s * freq;
    pe[idx] = (c & 1) ? cosf(ang) : sinf(ang);
}

// ---------------- weight prep ----------------
__global__ void prep_w(const float* __restrict__ WQ, const float* __restrict__ WK,
                       const float* __restrict__ cpw, const float* __restrict__ w1,
                       const float* __restrict__ w2,
                       us* __restrict__ wqS, us* __restrict__ wkT, us* __restrict__ pw16,
                       us* __restrict__ w1T, us* __restrict__ w2Tp) {
    int idx = blockIdx.x * 256 + threadIdx.x;
    if (idx >= H * D * D) return;  // 36864
    int h = idx / (D * D), rem = idx - h * (D * D);
    int d = rem / D, e = rem - d * D;
    int n = e >> 4, lmod = e & 15, kk = d >> 5, ldiv = (d >> 3) & 3, j = d & 7;
    wqS[(size_t)(((h * 6 + n) * 3 + kk) * 64 + ldiv * 16 + lmod) * 8 + j] = f2h(WQ[idx] * SQRTD);
    wkT[(size_t)h * D * D + e * D + d] = f2h(WK[idx]);
    pw16[idx] = f2h(cpw[idx]);  // L*D*D == 36864
    if (idx < 48 * 96) {
        int m = idx / 96, c = idx - m * 96;
        w1T[idx] = f2h(w1[c * 48 + m]);
    }
    if (idx < 96 * 64) {
        int o = idx / 64, m = idx - o * 64;
        w2Tp[idx] = (m < 48) ? f2h(w2[m * 96 + o]) : (us)0;
    }
}

// ---------------- WVO_h = WV_h @ WO_h, stored transposed [h][o][d] ----------------
__global__ void prep_wvo(const float* __restrict__ WV, const float* __restrict__ WO,
                         us* __restrict__ wvoT) {
    int blk = blockIdx.x;  // 24 = H * 6
    int h = blk / 6, ot = blk - h * 6;
    int tid = threadIdx.x;
    const float* wv = WV + (size_t)h * D * D;
    const float* wo = WO + (size_t)h * D * D;
    for (int i = tid; i < 16 * 96; i += 256) {
        int o = ot * 16 + i / 96, d = i - (i / 96) * 96;
        float acc = 0.f;
        for (int e = 0; e < 96; e++) acc += wv[d * 96 + e] * wo[e * 96 + o];
        wvoT[(size_t)h * D * D + o * 96 + d] = f2h(acc);
    }
}

// ---------------- conv0: embed + LN0 (halo inline) + dw + pw + residual + LN1 ----------------
__global__ void conv0f(const float* __restrict__ in, const float* __restrict__ pe,
                       const float* __restrict__ g0, const float* __restrict__ b0,
                       float* __restrict__ xout, us* __restrict__ lnout,
                       const float* __restrict__ dwW, const float* __restrict__ dwB,
                       const us* __restrict__ pwW, const float* __restrict__ pwb,
                       const float* __restrict__ gnext, const float* __restrict__ bnext) {
    __shared__ us lnb_s[70 * 104];
    __shared__ us dwb_s[64 * 104];
    __shared__ float lw[96 * 8];
    int tid = threadIdx.x;
    int wave = tid >> 6, lane = tid & 63;
    int r0 = blockIdx.x * 64;
    int b = r0 / S, s0 = r0 % S;

    for (int i = tid; i < 96 * KW; i += 256) lw[(i / KW) * 8 + (i % KW)] = dwW[i];

    for (int i = wave; i < 70; i += 4) {
        int s = s0 - 3 + i;
        bool valid = (unsigned)s < (unsigned)S;
        float v0 = 0.f, v1 = 0.f;
        if (valid) {
            size_t ro = ((size_t)b * S + s) * 96;
            v0 = in[ro + lane] * SQRTD + pe[s * 96 + lane];
            v1 = (lane < 32) ? in[ro + 64 + lane] * SQRTD + pe[s * 96 + 64 + lane] : 0.f;
        }
        float sm = v0 + v1, q = v0 * v0 + v1 * v1;
        for (int off = 32; off > 0; off >>= 1) {
            sm += __shfl_xor(sm, off);
            q += __shfl_xor(q, off);
        }
        float mean = sm * (1.0f / D);
        float var = q * (1.0f / D) - mean * mean;
        float rstd = rsqrtf(var + 1e-5f);
        lnb_s[i * 104 + lane] = f2h(valid ? (v0 - mean) * rstd * g0[lane] + b0[lane] : 0.f);
        if (lane < 32)
            lnb_s[i * 104 + 64 + lane] =
                f2h(valid ? (v1 - mean) * rstd * g0[lane + 64] + b0[lane + 64] : 0.f);
    }
    __syncthreads();

    for (int u = tid; u < 768; u += 256) {
        int j = u / 12, c0 = (u - (u / 12) * 12) * 8;
        float acc[8];
        #pragma unroll
        for (int j2 = 0; j2 < 8; j2++) acc[j2] = dwB[c0 + j2];
        #pragma unroll
        for (int k = 0; k < KW; k++) {
            f16x8 v = ldh(&lnb_s[(j + k) * 104 + c0]);
            #pragma unroll
            for (int j2 = 0; j2 < 8; j2++) acc[j2] += (float)v[j2] * lw[(c0 + j2) * 8 + k];
        }
        us8 o;
        #pragma unroll
        for (int j2 = 0; j2 < 8; j2++) o[j2] = f2h(acc[j2]);
        *reinterpret_cast<us8*>(&dwb_s[j * 104 + c0]) = o;
    }
    __syncthreads();

    int lmod = lane & 15, ldiv = lane >> 4, m0 = wave * 16;
    f32x4 acc[6] = {};
    #pragma unroll
    for (int kk = 0; kk < 3; kk++) {
        f16x8 af = ldh(&dwb_s[(m0 + lmod) * 104 + kk * 32 + ldiv * 8]);
        #pragma unroll
        for (int n = 0; n < 6; n++) {
            f16x8 bf = ldh(pwW + (size_t)(n * 16 + lmod) * 96 + kk * 32 + ldiv * 8);
            acc[n] = __builtin_amdgcn_mfma_f32_16x16x32_f16(af, bf, acc[n], 0, 0, 0);
        }
    }

    float gv[6], bv2[6], pb[6];
    #pragma unroll
    for (int n = 0; n < 6; n++) {
        int o = n * 16 + lmod;
        gv[n] = gnext[o];
        bv2[n] = bnext[o];
        pb[n] = pwb[o];
    }
    #pragma unroll
    for (int n = 0; n < 6; n++) {
        int o = n * 16 + lmod;
        #pragma unroll
        for (int r = 0; r < 4; r++) {
            int sr = m0 + ldiv * 4 + r;
            size_t row = (size_t)r0 + sr;
            float base = in[row * 96 + o] * SQRTD + pe[(s0 + sr) * 96 + o];
            acc[n][r] = base + fmaxf(acc[n][r] + pb[n], 0.f);
        }
    }
    #pragma unroll
    for (int r = 0; r < 4; r++) {
        float sm = 0.f, qq = 0.f;
        #pragma unroll
        for (int n = 0; n < 6; n++) {
            sm += acc[n][r];
            qq += acc[n][r] * acc[n][r];
        }
        #pragma unroll
        for (int st = 1; st <= 8; st <<= 1) {
            sm += __shfl_xor(sm, st);
            qq += __shfl_xor(qq, st);
        }
        float mean = sm * (1.0f / D);
        float var = qq * (1.0f / D) - mean * mean;
        float rstd = rsqrtf(var + 1e-5f);
        size_t row = (size_t)r0 + m0 + ldiv * 4 + r;
        #pragma unroll
        for (int n = 0; n < 6; n++) {
            int o = n * 16 + lmod;
            xout[row * 96 + o] = acc[n][r];
            lnout[row * 96 + o] = f2h((acc[n][r] - mean) * rstd * gv[n] + bv2[n]);
        }
    }
}

// ---------------- mid conv layer ----------------
__global__ void conv2(const float* __restrict__ xin, const us* __restrict__ lnin,
                      float* __restrict__ xout, us* __restrict__ lnout,
                      const float* __restrict__ dwW, const float* __restrict__ dwB,
                      const us* __restrict__ pwW, const float* __restrict__ pwb,
                      const float* __restrict__ gnext, const float* __restrict__ bnext) {
    __shared__ us dwb_s[64 * 104];
    __shared__ float lw[96 * 8];
    int tid = threadIdx.x;
    int wave = tid >> 6, lane = tid & 63;
    int r0 = blockIdx.x * 64;
    int b = r0 / S, s0 = r0 % S;

    for (int i = tid; i < 96 * KW; i += 256) lw[(i / KW) * 8 + (i % KW)] = dwW[i];
    __syncthreads();

    for (int u = tid; u < 768; u += 256) {
        int j = u / 12, c0 = (u - (u / 12) * 12) * 8;
        float acc[8];
        #pragma unroll
        for (int j2 = 0; j2 < 8; j2++) acc[j2] = dwB[c0 + j2];
        #pragma unroll
        for (int k = 0; k < KW; k++) {
            int ss = s0 + j + k - 3;
            if ((unsigned)ss < (unsigned)S) {
                f16x8 v = ldh(lnin + ((size_t)b * S + ss) * 96 + c0);
                #pragma unroll
                for (int j2 = 0; j2 < 8; j2++) acc[j2] += (float)v[j2] * lw[(c0 + j2) * 8 + k];
            }
        }
        us8 o;
        #pragma unroll
        for (int j2 = 0; j2 < 8; j2++) o[j2] = f2h(acc[j2]);
        *reinterpret_cast<us8*>(&dwb_s[j * 104 + c0]) = o;
    }
    __syncthreads();

    int lmod = lane & 15, ldiv = lane >> 4, m0 = wave * 16;
    f32x4 acc[6] = {};
    #pragma unroll
    for (int kk = 0; kk < 3; kk++) {
        f16x8 af = ldh(&dwb_s[(m0 + lmod) * 104 + kk * 32 + ldiv * 8]);
        #pragma unroll
        for (int n = 0; n < 6; n++) {
            f16x8 bf = ldh(pwW + (size_t)(n * 16 + lmod) * 96 + kk * 32 + ldiv * 8);
            acc[n] = __builtin_amdgcn_mfma_f32_16x16x32_f16(af, bf, acc[n], 0, 0, 0);
        }
    }

    float gv[6], bv2[6], pb[6];
    #pragma unroll
    for (int n = 0; n < 6; n++) {
        int o = n * 16 + lmod;
        gv[n] = gnext[o];
        bv2[n] = bnext[o];
        pb[n] = pwb[o];
    }
    #pragma unroll
    for (int n = 0; n < 6; n++) {
        #pragma unroll
        for (int r = 0; r < 4; r++) {
            size_t row = (size_t)r0 + m0 + ldiv * 4 + r;
            acc[n][r] = xin[row * 96 + n * 16 + lmod] + fmaxf(acc[n][r] + pb[n], 0.f);
        }
    }
    #pragma unroll
    for (int r = 0; r < 4; r++) {
        float sm = 0.f, qq = 0.f;
        #pragma unroll
        for (int n = 0; n < 6; n++) {
            sm += acc[n][r];
            qq += acc[n][r] * acc[n][r];
        }
        #pragma unroll
        for (int st = 1; st <= 8; st <<= 1) {
            sm += __shfl_xor(sm, st);
            qq += __shfl_xor(qq, st);
        }
        float mean = sm * (1.0f / D);
        float var = qq * (1.0f / D) - mean * mean;
        float rstd = rsqrtf(var + 1e-5f);
        size_t row = (size_t)r0 + m0 + ldiv * 4 + r;
        #pragma unroll
        for (int n = 0; n < 6; n++) {
            int o = n * 16 + lmod;
            xout[row * 96 + o] = acc[n][r];
            lnout[row * 96 + o] = f2h((acc[n][r] - mean) * rstd * gv[n] + bv2[n]);
        }
    }
}

// ---------------- conv3 + K/V' projection fused (V chunk-major layout) ----------------
__global__ void conv3p(const float* __restrict__ xin, const us* __restrict__ lnin,
                       float* __restrict__ xout, us* __restrict__ lnout,
                       const float* __restrict__ dwW, const float* __restrict__ dwB,
                       const us* __restrict__ pwW, const float* __restrict__ pwb,
                       const float* __restrict__ gnext, const float* __restrict__ bnext,
                       const us* __restrict__ wkT, const us* __restrict__ wvoT,
                       us* __restrict__ Kall, us* __restrict__ Vall) {
    __shared__ float lw[96 * 8];
    __shared__ us stg[96 * 72];
    __shared__ us lnstg[64 * 104];
    int tid = threadIdx.x;
    int wave = tid >> 6, lane = tid & 63;
    int lmod = lane & 15, ldiv = lane >> 4, m0 = wave * 16;
    int r0 = blockIdx.x * 64;
    int b = r0 / S, s0 = r0 % S;

    for (int i = tid; i < 96 * KW; i += 256) lw[(i / KW) * 8 + (i % KW)] = dwW[i];
    __syncthreads();

    for (int u = tid; u < 768; u += 256) {
        int j = u / 12, c0 = (u - (u / 12) * 12) * 8;
        float acc[8];
        #pragma unroll
        for (int j2 = 0; j2 < 8; j2++) acc[j2] = dwB[c0 + j2];
        #pragma unroll
        for (int k = 0; k < KW; k++) {
            int ss = s0 + j + k - 3;
            if ((unsigned)ss < (unsigned)S) {
                f16x8 v = ldh(lnin + ((size_t)b * S + ss) * 96 + c0);
                #pragma unroll
                for (int j2 = 0; j2 < 8; j2++) acc[j2] += (float)v[j2] * lw[(c0 + j2) * 8 + k];
            }
        }
        us8 o;
        #pragma unroll
        for (int j2 = 0; j2 < 8; j2++) o[j2] = f2h(acc[j2]);
        *reinterpret_cast<us8*>(&stg[j * 104 + c0]) = o;
    }
    __syncthreads();

    f32x4 acc[6] = {};
    #pragma unroll
    for (int kk = 0; kk < 3; kk++) {
        f16x8 af = ldh(&stg[(m0 + lmod) * 104 + kk * 32 + ldiv * 8]);
        #pragma unroll
        for (int n = 0; n < 6; n++) {
            f16x8 bf = ldh(pwW + (size_t)(n * 16 + lmod) * 96 + kk * 32 + ldiv * 8);
            acc[n] = __builtin_amdgcn_mfma_f32_16x16x32_f16(af, bf, acc[n], 0, 0, 0);
        }
    }

    float gv[6], bv2[6], pb[6];
    #pragma unroll
    for (int n = 0; n < 6; n++) {
        int o = n * 16 + lmod;
        gv[n] = gnext[o];
        bv2[n] = bnext[o];
        pb[n] = pwb[o];
    }
    #pragma unroll
    for (int n = 0; n < 6; n++) {
        #pragma unroll
        for (int r = 0; r < 4; r++) {
            size_t row = (size_t)r0 + m0 + ldiv * 4 + r;
            acc[n][r] = xin[row * 96 + n * 16 + lmod] + fmaxf(acc[n][r] + pb[n], 0.f);
        }
    }
    #pragma unroll
    for (int r = 0; r < 4; r++) {
        float sm = 0.f, qq = 0.f;
        #pragma unroll
        for (int n = 0; n < 6; n++) {
            sm += acc[n][r];
            qq += acc[n][r] * acc[n][r];
        }
        #pragma unroll
        for (int st = 1; st <= 8; st <<= 1) {
            sm += __shfl_xor(sm, st);
            qq += __shfl_xor(qq, st);
        }
        float mean = sm * (1.0f / D);
        float var = qq * (1.0f / D) - mean * mean;
        float rstd = rsqrtf(var + 1e-5f);
        size_t row = (size_t)r0 + m0 + ldiv * 4 + r;
        #pragma unroll
        for (int n = 0; n < 6; n++) {
            int o = n * 16 + lmod;
            xout[row * 96 + o] = acc[n][r];
            us hv = f2h((acc[n][r] - mean) * rstd * gv[n] + bv2[n]);
            lnout[row * 96 + o] = hv;
            lnstg[(m0 + ldiv * 4 + r) * 104 + o] = hv;
        }
    }
    __syncthreads();

    f16x8 af[3];
    #pragma unroll
    for (int kk = 0; kk < 3; kk++)
        af[kk] = ldh(&lnstg[(m0 + lmod) * 104 + kk * 32 + ldiv * 8]);

    for (int hd = 0; hd < H; hd++) {
        // ---- K ----
        f32x4 ka[6] = {};
        #pragma unroll
        for (int kk = 0; kk < 3; kk++)
            #pragma unroll
            for (int n = 0; n < 6; n++) {
                f16x8 bf =
                    ldh(wkT + (size_t)hd * D * D + (size_t)(n * 16 + lmod) * 96 + kk * 32 + ldiv * 8);
                ka[n] = __builtin_amdgcn_mfma_f32_16x16x32_f16(af[kk], bf, ka[n], 0, 0, 0);
            }
        __syncthreads();
        us* kT = stg + wave * 1664;
        #pragma unroll
        for (int n = 0; n < 6; n++)
            #pragma unroll
            for (int r = 0; r < 4; r++)
                kT[(ldiv * 4 + r) * 104 + n * 16 + lmod] = f2h(ka[n][r]);
        int t0 = (r0 % S) / 16 + wave;
        us* dst = Kall + (size_t)hd * NTOT + ((size_t)(b * 24 + t0) * 3) * 512;
        #pragma unroll
        for (int kk = 0; kk < 3; kk++) {
            us8 v = *reinterpret_cast<const us8*>(&kT[lmod * 104 + kk * 32 + ldiv * 8]);
            *reinterpret_cast<us8*>(dst + kk * 512 + lane * 8) = v;
        }
        // ---- V' ---- (chunk-major: [b][cblk][n][kk][lane][8])
        f32x4 va[6] = {};
        #pragma unroll
        for (int kk = 0; kk < 3; kk++)
            #pragma unroll
            for (int n = 0; n < 6; n++) {
                f16x8 bf = ldh(wvoT + (size_t)hd * D * D + (size_t)(n * 16 + lmod) * 96 + kk * 32 +
                               ldiv * 8);
                va[n] = __builtin_amdgcn_mfma_f32_16x16x32_f16(af[kk], bf, va[n], 0, 0, 0);
            }
        __syncthreads();
        #pragma unroll
        for (int n = 0; n < 6; n++)
            #pragma unroll
            for (int r = 0; r < 4; r++)
                stg[(n * 16 + lmod) * 72 + m0 + ldiv * 4 + r] = f2h(va[n][r]);
        __syncthreads();
        int cblk = (r0 % S) / 64;
        us* dsth = Vall + (size_t)hd * NTOT;
        #pragma unroll
        for (int n = 0; n < 6; n++)
            #pragma unroll
            for (int kk = 0; kk < 2; kk++) {
                us8 v =
                    *reinterpret_cast<const us8*>(&stg[(n * 16 + lmod) * 72 + kk * 32 + ldiv * 8]);
                *reinterpret_cast<us8*>(
                    dsth + ((size_t)((b * 6 + cblk) * 6 + n) * 2 + kk) * 512 + lane * 8) = v;
            }
    }
}

// ---------------- block-cooperative LDS-staged attention ----------------
// grid 1536 = 128 b x 4 hd x 3 qthird; 4 waves x 32 q-rows; K/V dbuf in LDS.
__global__ __launch_bounds__(256, 2) void attn_g(const us* __restrict__ h16,
                                                 const us* __restrict__ wqS,
                                                 const us* __restrict__ Kall,
                                                 const us* __restrict__ Vall,
                                                 us* __restrict__ xpart) {
    __shared__ us Kb[2][6144];
    __shared__ us Vb[2][6144];
    __shared__ us Pq[4][3328];  // per-wave: Q staging stride 104, then P stride 72
    int tid = threadIdx.x, wave = tid >> 6, lane = tid & 63;
    int lmod = lane & 15, ldiv = lane >> 4;
    int p = blockIdx.x;
    int gl = (p & 7) * 192 + (p >> 3);  // XCD swizzle, 1536 = 8*192
    int qt = gl % 3;
    int bh = gl / 3;
    int b = bh >> 2, hd = bh & 3;
    size_t rowbase = (size_t)b * S + qt * 128 + wave * 32;

    const us* Kh = Kall + (size_t)hd * NTOT + (size_t)b * 24 * 1536;
    const us* Vh = Vall + (size_t)hd * NTOT + (size_t)b * 36 * 1024;
    us* P = Pq[wave];

    // prologue: issue K0 staging loads, Q-proj under their latency
    us8 kst[3];
    #pragma unroll
    for (int j = 0; j < 3; j++)
        kst[j] = *reinterpret_cast<const us8*>(Kh + (size_t)(j * 256 + tid) * 8);

    f32x4 qa0[6] = {}, qa1[6] = {};
    #pragma unroll
    for (int kk = 0; kk < 3; kk++) {
        f16x8 a0 = ldh(h16 + (rowbase + lmod) * 96 + kk * 32 + ldiv * 8);
        f16x8 a1 = ldh(h16 + (rowbase + 16 + lmod) * 96 + kk * 32 + ldiv * 8);
        #pragma unroll
        for (int n = 0; n < 6; n++) {
            f16x8 bf = ldh(wqS + (size_t)(((hd * 6 + n) * 3 + kk) * 64) * 8 + lane * 8);
            qa0[n] = __builtin_amdgcn_mfma_f32_16x16x32_f16(a0, bf, qa0[n], 0, 0, 0);
            qa1[n] = __builtin_amdgcn_mfma_f32_16x16x32_f16(a1, bf, qa1[n], 0, 0, 0);
        }
    }
    #pragma unroll
    for (int n = 0; n < 6; n++)
        #pragma unroll
        for (int r = 0; r < 4; r++) {
            P[(ldiv * 4 + r) * 104 + n * 16 + lmod] = f2h(qa0[n][r]);
            P[(16 + ldiv * 4 + r) * 104 + n * 16 + lmod] = f2h(qa1[n][r]);
        }
    f16x8 aq0[3], aq1[3];
    #pragma unroll
    for (int kk = 0; kk < 3; kk++) {
        aq0[kk] = ldh(&P[lmod * 104 + kk * 32 + ldiv * 8]);
        aq1[kk] = ldh(&P[(16 + lmod) * 104 + kk * 32 + ldiv * 8]);
    }
    #pragma unroll
    for (int j = 0; j < 3; j++)
        *reinterpret_cast<us8*>(&Kb[0][(j * 256 + tid) * 8]) = kst[j];
    __syncthreads();

    // ---- pass 1: row max (K staged, single-type) ----
    f32x4 mx0 = {-1e30f, -1e30f, -1e30f, -1e30f}, mx1 = mx0;
    for (int c = 0; c < 6; c++) {
        int cur = c & 1, nxt = cur ^ 1;
        us8 kn[3], vn[3];
        bool last = (c == 5);
        if (!last) {
            #pragma unroll
            for (int j = 0; j < 3; j++)
                kn[j] = *reinterpret_cast<const us8*>(Kh + (size_t)(c + 1) * 6144 +
                                                      (size_t)(j * 256 + tid) * 8);
        } else {
            // stage K0 + V0 for pass 2
            #pragma unroll
            for (int j = 0; j < 3; j++) {
                kn[j] = *reinterpret_cast<const us8*>(Kh + (size_t)(j * 256 + tid) * 8);
                vn[j] = *reinterpret_cast<const us8*>(Vh + (size_t)(j * 256 + tid) * 8);
            }
        }
        __builtin_amdgcn_s_setprio(1);
        f32x4 s0[4] = {}, s1[4] = {};
        #pragma unroll
        for (int nt = 0; nt < 4; nt++)
            #pragma unroll
            for (int kk = 0; kk < 3; kk++) {
                f16x8 bf = ldh(&Kb[cur][(nt * 3 + kk) * 512 + lane * 8]);
                s0[nt] = __builtin_amdgcn_mfma_f32_16x16x32_f16(aq0[kk], bf, s0[nt], 0, 0, 0);
                s1[nt] = __builtin_amdgcn_mfma_f32_16x16x32_f16(aq1[kk], bf, s1[nt], 0, 0, 0);
            }
        __builtin_amdgcn_s_setprio(0);
        #pragma unroll
        for (int nt = 0; nt < 4; nt++)
            #pragma unroll
            for (int r = 0; r < 4; r++) {
                mx0[r] = fmaxf(mx0[r], s0[nt][r]);
                mx1[r] = fmaxf(mx1[r], s1[nt][r]);
            }
        int wb = last ? 0 : nxt;
        #pragma unroll
        for (int j = 0; j < 3; j++)
            *reinterpret_cast<us8*>(&Kb[wb][(j * 256 + tid) * 8]) = kn[j];
        if (last) {
            #pragma unroll
            for (int j = 0; j < 3; j++)
                *reinterpret_cast<us8*>(&Vb[0][(j * 256 + tid) * 8]) = vn[j];
        }
        __syncthreads();
    }
    #pragma unroll
    for (int st = 1; st <= 8; st <<= 1)
        #pragma unroll
        for (int r = 0; r < 4; r++) {
            mx0[r] = fmaxf(mx0[r], __shfl_xor(mx0[r], st));
            mx1[r] = fmaxf(mx1[r], __shfl_xor(mx1[r], st));
        }

    // ---- pass 2: scores -> exp -> PV (K+V staged) ----
    f32x4 oacc0[6] = {}, oacc1[6] = {};
    f32x4 l0v = {}, l1v = {};
    for (int c = 0; c < 6; c++) {
        int cur = c & 1, nxt = cur ^ 1;
        us8 kn[3], vn[3];
        if (c < 5) {
            #pragma unroll
            for (int j = 0; j < 3; j++) {
                kn[j] = *reinterpret_cast<const us8*>(Kh + (size_t)(c + 1) * 6144 +
                                                      (size_t)(j * 256 + tid) * 8);
                vn[j] = *reinterpret_cast<const us8*>(Vh + (size_t)(c + 1) * 6144 +
                                                      (size_t)(j * 256 + tid) * 8);
            }
        }
        __builtin_amdgcn_s_setprio(1);
        f32x4 s0[4] = {}, s1[4] = {};
        #pragma unroll
        for (int nt = 0; nt < 4; nt++)
            #pragma unroll
            for (int kk = 0; kk < 3; kk++) {
                f16x8 bf = ldh(&Kb[cur][(nt * 3 + kk) * 512 + lane * 8]);
                s0[nt] = __builtin_amdgcn_mfma_f32_16x16x32_f16(aq0[kk], bf, s0[nt], 0, 0, 0);
                s1[nt] = __builtin_amdgcn_mfma_f32_16x16x32_f16(aq1[kk], bf, s1[nt], 0, 0, 0);
            }
        __builtin_amdgcn_s_setprio(0);
        #pragma unroll
        for (int nt = 0; nt < 4; nt++)
            #pragma unroll
            for (int r = 0; r < 4; r++) {
                float p0 = __expf(s0[nt][r] - mx0[r]);
                float p1 = __expf(s1[nt][r] - mx1[r]);
                l0v[r] += p0;
                l1v[r] += p1;
                P[(ldiv * 4 + r) * 72 + nt * 16 + lmod] = f2h(p0);
                P[(16 + ldiv * 4 + r) * 72 + nt * 16 + lmod] = f2h(p1);
            }
        __builtin_amdgcn_s_setprio(1);
        #pragma unroll
        for (int kk = 0; kk < 2; kk++) {
            f16x8 pf0 = ldh(&P[lmod * 72 + kk * 32 + ldiv * 8]);
            f16x8 pf1 = ldh(&P[(16 + lmod) * 72 + kk * 32 + ldiv * 8]);
            #pragma unroll
            for (int n = 0; n < 6; n++) {
                f16x8 bf = ldh(&Vb[cur][(n * 2 + kk) * 512 + lane * 8]);
                oacc0[n] = __builtin_amdgcn_mfma_f32_16x16x32_f16(pf0, bf, oacc0[n], 0, 0, 0);
                oacc1[n] = __builtin_amdgcn_mfma_f32_16x16x32_f16(pf1, bf, oacc1[n], 0, 0, 0);
            }
        }
        __builtin_amdgcn_s_setprio(0);
        if (c < 5) {
            #pragma unroll
            for (int j = 0; j < 3; j++) {
                *reinterpret_cast<us8*>(&Kb[nxt][(j * 256 + tid) * 8]) = kn[j];
                *reinterpret_cast<us8*>(&Vb[nxt][(j * 256 + tid) * 8]) = vn[j];
            }
            __syncthreads();
        }
    }
    #pragma unroll
    for (int st = 1; st <= 8; st <<= 1)
        #pragma unroll
        for (int r = 0; r < 4; r++) {
            l0v[r] += __shfl_xor(l0v[r], st);
            l1v[r] += __shfl_xor(l1v[r], st);
        }

    us* xp = xpart + (size_t)hd * NTOT;
    #pragma unroll
    for (int r = 0; r < 4; r++) {
        float inv0 = 1.f / l0v[r];
        float inv1 = 1.f / l1v[r];
        #pragma unroll
        for (int n = 0; n < 6; n++) {
            xp[(rowbase + ldiv * 4 + r) * 96 + n * 16 + lmod] = f2h(oacc0[n][r] * inv0);
            xp[(rowbase + 16 + ldiv * 4 + r) * 96 + n * 16 + lmod] = f2h(oacc1[n][r] * inv1);
        }
    }
}

// ---------------- fused head-reduce + LN + FFN ----------------
__global__ void ffn_ln(const float* __restrict__ x, const us* __restrict__ xpart,
                       const float* __restrict__ gln, const float* __restrict__ bln,
                       const us* __restrict__ w1T, const float* __restrict__ b1,
                       const us* __restrict__ w2Tp, const float* __restrict__ b2,
                       float* __restrict__ out) {
    __shared__ float xf[64 * 96];
    __shared__ us lnb[64 * 104];
    __shared__ us mid[64 * 72];
    int tid = threadIdx.x, wave = tid >> 6, lane = tid & 63;
    int lmod = lane & 15, ldiv = lane >> 4, m0 = wave * 16;
    int row0 = blockIdx.x * 64;

    for (int i = wave; i < 64; i += 4) {
        size_t ro = (size_t)(row0 + i) * 96;
        float v0 = x[ro + lane];
        float v1 = (lane < 32) ? x[ro + 64 + lane] : 0.f;
        #pragma unroll
        for (int h = 0; h < H; h++) {
            const us* xp = xpart + (size_t)h * NTOT + ro;
            v0 += (float)__builtin_bit_cast(_Float16, xp[lane]);
            if (lane < 32) v1 += (float)__builtin_bit_cast(_Float16, xp[64 + lane]);
        }
        xf[i * 96 + lane] = v0;
        if (lane < 32) xf[i * 96 + 64 + lane] = v1;
        float sm = v0 + v1, q = v0 * v0 + v1 * v1;
        for (int off = 32; off > 0; off >>= 1) {
            sm += __shfl_xor(sm, off);
            q += __shfl_xor(q, off);
        }
        float mean = sm * (1.0f / D);
        float var = q * (1.0f / D) - mean * mean;
        float rstd = rsqrtf(var + 1e-5f);
        lnb[i * 104 + lane] = f2h((v0 - mean) * rstd * gln[lane] + bln[lane]);
        if (lane < 32)
            lnb[i * 104 + 64 + lane] = f2h((v1 - mean) * rstd * gln[lane + 64] + bln[lane + 64]);
    }
    __syncthreads();

    f32x4 a3[3] = {};
    #pragma unroll
    for (int kk = 0; kk < 3; kk++) {
        f16x8 af = ldh(&lnb[(m0 + lmod) * 104 + kk * 32 + ldiv * 8]);
        #pragma unroll
        for (int n = 0; n < 3; n++) {
            f16x8 bf = ldh(w1T + (size_t)(n * 16 + lmod) * 96 + kk * 32 + ldiv * 8);
            a3[n] = __builtin_amdgcn_mfma_f32_16x16x32_f16(af, bf, a3[n], 0, 0, 0);
        }
    }
    #pragma unroll
    for (int n = 0; n < 3; n++) {
        float bv = b1[n * 16 + lmod];
        #pragma unroll
        for (int r = 0; r < 4; r++) {
            float v = a3[n][r] + bv;
            mid[(m0 + ldiv * 4 + r) * 72 + n * 16 + lmod] = f2h(1.f / (1.f + __expf(-v)));
        }
    }
    #pragma unroll
    for (int r = 0; r < 4; r++) mid[(m0 + ldiv * 4 + r) * 72 + 48 + lmod] = 0;
    __syncthreads();

    f32x4 a6[6] = {};
    #pragma unroll
    for (int kk = 0; kk < 2; kk++) {
        f16x8 af = ldh(&mid[(m0 + lmod) * 72 + kk * 32 + ldiv * 8]);
        #pragma unroll
        for (int n = 0; n < 6; n++) {
            f16x8 bf = ldh(w2Tp + (size_t)(n * 16 + lmod) * 64 + kk * 32 + ldiv * 8);
            a6[n] = __builtin_amdgcn_mfma_f32_16x16x32_f16(af, bf, a6[n], 0, 0, 0);
        }
    }
    #pragma unroll
    for (int n = 0; n < 6; n++) {
        int o = n * 16 + lmod;
        float bv = b2[o];
        #pragma unroll
        for (int r = 0; r < 4; r++) {
            int sr = m0 + ldiv * 4 + r;
            out[(size_t)(row0 + sr) * 96 + o] = xf[sr * 96 + o] + a6[n][r] + bv;
        }
    }
}

extern "C" void kernel_launch(void* const* d_in, const int* in_sizes, int n_in,
                              void* d_out, int out_size, void* d_ws, size_t ws_size,
                              hipStream_t stream) {
    const float* in   = (const float*)d_in[0];
    const float* cdw  = (const float*)d_in[2];
    const float* cdwb = (const float*)d_in[3];
    const float* cpw  = (const float*)d_in[4];
    const float* cpwb = (const float*)d_in[5];
    const float* WQ   = (const float*)d_in[6];
    const float* WK   = (const float*)d_in[7];
    const float* WV   = (const float*)d_in[8];
    const float* WO   = (const float*)d_in[9];
    const float* w1   = (const float*)d_in[10];
    const float* b1   = (const float*)d_in[11];
    const float* w2   = (const float*)d_in[12];
    const float* b2   = (const float*)d_in[13];
    const float* lng  = (const float*)d_in[14];
    const float* lnb  = (const float*)d_in[15];
    float* out = (float*)d_out;
    float* ws = (float*)d_ws;

    float* xA  = ws;
    float* xB  = xA + NTOT;
    float* pe  = xB + NTOT;
    us* lnA    = (us*)(pe + S * D);
    us* lnB    = lnA + NTOT;
    us* Kall   = lnB + NTOT;               // [H][B][24][3][64][8]
    us* Vall   = Kall + (size_t)H * NTOT;  // [H][B][6 c][6 n][2 kk][64][8]
    us* xpart  = Vall + (size_t)H * NTOT;  // [H][ROWS][96]
    us* wqS    = xpart + (size_t)H * NTOT;
    us* wkT    = wqS + H * D * D;
    us* wvoT   = wkT + H * D * D;
    us* pw16   = wvoT + H * D * D;
    us* w1T    = pw16 + L * D * D;
    us* w2Tp   = w1T + 48 * 96;
    // total ~= 170 MB (< 256 MB ws)

    pe_kernel<<<(S * D + 255) / 256, 256, 0, stream>>>(pe);
    prep_w<<<(H * D * D + 255) / 256, 256, 0, stream>>>(WQ, WK, cpw, w1, w2,
                                                        wqS, wkT, pw16, w1T, w2Tp);
    prep_wvo<<<H * 6, 256, 0, stream>>>(WV, WO, wvoT);

    conv0f<<<ROWS / 64, 256, 0, stream>>>(in, pe, lng, lnb, xA, lnB,
                                          cdw, cdwb, pw16, cpwb, lng + D, lnb + D);
    conv2<<<ROWS / 64, 256, 0, stream>>>(xA, lnB, xB, lnA, cdw + D * KW, cdwb + D,
                                         pw16 + D * D, cpwb + D, lng + 2 * D, lnb + 2 * D);
    conv2<<<ROWS / 64, 256, 0, stream>>>(xB, lnA, xA, lnB, cdw + 2 * D * KW, cdwb + 2 * D,
                                         pw16 + 2 * D * D, cpwb + 2 * D, lng + 3 * D,
                                         lnb + 3 * D);
    conv3p<<<ROWS / 64, 256, 0, stream>>>(xA, lnB, xB, lnA, cdw + 3 * D * KW, cdwb + 3 * D,
                                          pw16 + 3 * D * D, cpwb + 3 * D, lng + 4 * D,
                                          lnb + 4 * D, wkT, wvoT, Kall, Vall);

    // lnA == h16, xB == x4
    attn_g<<<1536, 256, 0, stream>>>(lnA, wqS, Kall, Vall, xpart);

    ffn_ln<<<ROWS / 64, 256, 0, stream>>>(xB, xpart, lng + 5 * D, lnb + 5 * D,
                                          w1T, b1, w2Tp, b2, out);
}

// Round 18
// 280.051 us; speedup vs baseline: 1.2063x; 1.0874x over previous
//
#include <hip/hip_runtime.h>
#include <math.h>

// EmbeddingEncoder: B=128, S=384, D=96, H=4, K=7, L=4.
// Round 18: ALL weight B-fragments in fragment order [n][kk][lane][8]
// (pw, wk, wvo, w1, w2 — like wqS since r7). Kills the 16-way 192B-stride
// gathers in conv0/conv2/conv3p/ffn_ln. Structure otherwise = round 17 (304 us).

constexpr int B = 128;
constexpr int S = 384;
constexpr int D = 96;
constexpr int H = 4;
constexpr int KW = 7;
constexpr int L = 4;
constexpr int ROWS = B * S;                      // 49152
constexpr long long NTOT = (long long)ROWS * D;  // 4718592
constexpr float SQRTD = 9.797958971132712f;

typedef _Float16 f16x8 __attribute__((ext_vector_type(8)));
typedef float f32x4 __attribute__((ext_vector_type(4)));
typedef unsigned short us;
typedef unsigned short us8 __attribute__((ext_vector_type(8)));

__device__ __forceinline__ us f2h(float f) {
    _Float16 h = (_Float16)f;
    return __builtin_bit_cast(us, h);
}
__device__ __forceinline__ f16x8 ldh(const us* p) {
    return *reinterpret_cast<const f16x8*>(p);
}

// ---------------- positional encoding ----------------
__global__ void pe_kernel(float* __restrict__ pe) {
    int idx = blockIdx.x * 256 + threadIdx.x;
    if (idx >= S * D) return;
    int s = idx / D, c = idx - s * D;
    int j = c >> 1;
    float expo = (c & 1) ? (4.0f * j + 2.0f) / 96.0f : (4.0f * j) / 96.0f;
    float freq = expf(-expo * logf(10000.0f));
    float ang = (float)s * freq;
    pe[idx] = (c & 1) ? cosf(ang) : sinf(ang);
}

// ---------------- weight prep (ALL weights to fragment order) ----------------
// frag index for B element (row = n*16+lmod, col = kk*32+ldiv*8+j):
//   [((n*NK + kk)*64 + ldiv*16 + lmod)*8 + j]
__global__ void prep_w(const float* __restrict__ WQ, const float* __restrict__ WK,
                       const float* __restrict__ cpw, const float* __restrict__ w1,
                       const float* __restrict__ w2,
                       us* __restrict__ wqS, us* __restrict__ wkS, us* __restrict__ pwS,
                       us* __restrict__ w1S, us* __restrict__ w2S) {
    int idx = blockIdx.x * 256 + threadIdx.x;
    if (idx >= H * D * D) return;  // 36864
    int h = idx / (D * D), rem = idx - h * (D * D);
    int d = rem / D, e = rem - d * D;
    int n = e >> 4, lmod = e & 15, kk = d >> 5, ldiv = (d >> 3) & 3, j = d & 7;
    size_t fi = (size_t)(((n * 3 + kk) * 64 + ldiv * 16 + lmod) * 8 + j);
    wqS[(size_t)h * D * D + fi] = f2h(WQ[idx] * SQRTD);
    wkS[(size_t)h * D * D + fi] = f2h(WK[idx]);
    // pw: cpw layout [l][o][c]; B element (row o, col c)
    {
        int l = idx / (D * D);
        int o = rem / D, c = rem - o * D;  // same decomposition
        int no = o >> 4, lo = o & 15, kc = c >> 5, lc = (c >> 3) & 3, jc = c & 7;
        pwS[(size_t)l * D * D + (size_t)(((no * 3 + kc) * 64 + lc * 16 + lo) * 8 + jc)] =
            f2h(cpw[idx]);
    }
    if (idx < 48 * 96) {  // w1: [96 c][48 m]; B element (row m, col c)
        int m = idx / 96, c = idx - m * 96;
        int nm = m >> 4, lm = m & 15, kc = c >> 5, lc = (c >> 3) & 3, jc = c & 7;
        w1S[((nm * 3 + kc) * 64 + lc * 16 + lm) * 8 + jc] = f2h(w1[c * 48 + m]);
    }
    if (idx < 96 * 64) {  // w2: [48 m][96 o]; B element (row o, col mk<64 padded)
        int o = idx / 64, mk = idx - o * 64;
        int no = o >> 4, lo = o & 15, km = mk >> 5, lm2 = (mk >> 3) & 3, jm = mk & 7;
        w2S[((no * 2 + km) * 64 + lm2 * 16 + lo) * 8 + jm] =
            (mk < 48) ? f2h(w2[mk * 96 + o]) : (us)0;
    }
}

// ---------------- WVO_h = WV_h @ WO_h -> fragment order ----------------
__global__ void prep_wvo(const float* __restrict__ WV, const float* __restrict__ WO,
                         us* __restrict__ wvoS) {
    int blk = blockIdx.x;  // 24 = H * 6
    int h = blk / 6, ot = blk - h * 6;
    int tid = threadIdx.x;
    const float* wv = WV + (size_t)h * D * D;
    const float* wo = WO + (size_t)h * D * D;
    for (int i = tid; i < 16 * 96; i += 256) {
        int lmod = i / 96, d = i - (i / 96) * 96;
        int o = ot * 16 + lmod;
        float acc = 0.f;
        for (int e = 0; e < 96; e++) acc += wv[d * 96 + e] * wo[e * 96 + o];
        int kk = d >> 5, ldiv = (d >> 3) & 3, j = d & 7;
        wvoS[(size_t)h * D * D + (size_t)(((ot * 3 + kk) * 64 + ldiv * 16 + lmod) * 8 + j)] =
            f2h(acc);
    }
}

// ---------------- conv0: embed + LN0 (halo inline) + dw + pw + residual + LN1 ----------------
__global__ void conv0f(const float* __restrict__ in, const float* __restrict__ pe,
                       const float* __restrict__ g0, const float* __restrict__ b0,
                       float* __restrict__ xout, us* __restrict__ lnout,
                       const float* __restrict__ dwW, const float* __restrict__ dwB,
                       const us* __restrict__ pwW, const float* __restrict__ pwb,
                       const float* __restrict__ gnext, const float* __restrict__ bnext) {
    __shared__ us lnb_s[70 * 104];
    __shared__ us dwb_s[64 * 104];
    __shared__ float lw[96 * 8];
    int tid = threadIdx.x;
    int wave = tid >> 6, lane = tid & 63;
    int r0 = blockIdx.x * 64;
    int b = r0 / S, s0 = r0 % S;

    for (int i = tid; i < 96 * KW; i += 256) lw[(i / KW) * 8 + (i % KW)] = dwW[i];

    for (int i = wave; i < 70; i += 4) {
        int s = s0 - 3 + i;
        bool valid = (unsigned)s < (unsigned)S;
        float v0 = 0.f, v1 = 0.f;
        if (valid) {
            size_t ro = ((size_t)b * S + s) * 96;
            v0 = in[ro + lane] * SQRTD + pe[s * 96 + lane];
            v1 = (lane < 32) ? in[ro + 64 + lane] * SQRTD + pe[s * 96 + 64 + lane] : 0.f;
        }
        float sm = v0 + v1, q = v0 * v0 + v1 * v1;
        for (int off = 32; off > 0; off >>= 1) {
            sm += __shfl_xor(sm, off);
            q += __shfl_xor(q, off);
        }
        float mean = sm * (1.0f / D);
        float var = q * (1.0f / D) - mean * mean;
        float rstd = rsqrtf(var + 1e-5f);
        lnb_s[i * 104 + lane] = f2h(valid ? (v0 - mean) * rstd * g0[lane] + b0[lane] : 0.f);
        if (lane < 32)
            lnb_s[i * 104 + 64 + lane] =
                f2h(valid ? (v1 - mean) * rstd * g0[lane + 64] + b0[lane + 64] : 0.f);
    }
    __syncthreads();

    for (int u = tid; u < 768; u += 256) {
        int j = u / 12, c0 = (u - (u / 12) * 12) * 8;
        float acc[8];
        #pragma unroll
        for (int j2 = 0; j2 < 8; j2++) acc[j2] = dwB[c0 + j2];
        #pragma unroll
        for (int k = 0; k < KW; k++) {
            f16x8 v = ldh(&lnb_s[(j + k) * 104 + c0]);
            #pragma unroll
            for (int j2 = 0; j2 < 8; j2++) acc[j2] += (float)v[j2] * lw[(c0 + j2) * 8 + k];
        }
        us8 o;
        #pragma unroll
        for (int j2 = 0; j2 < 8; j2++) o[j2] = f2h(acc[j2]);
        *reinterpret_cast<us8*>(&dwb_s[j * 104 + c0]) = o;
    }
    __syncthreads();

    int lmod = lane & 15, ldiv = lane >> 4, m0 = wave * 16;
    f32x4 acc[6] = {};
    #pragma unroll
    for (int kk = 0; kk < 3; kk++) {
        f16x8 af = ldh(&dwb_s[(m0 + lmod) * 104 + kk * 32 + ldiv * 8]);
        #pragma unroll
        for (int n = 0; n < 6; n++) {
            f16x8 bf = ldh(pwW + (size_t)((n * 3 + kk) * 64) * 8 + lane * 8);
            acc[n] = __builtin_amdgcn_mfma_f32_16x16x32_f16(af, bf, acc[n], 0, 0, 0);
        }
    }

    float gv[6], bv2[6], pb[6];
    #pragma unroll
    for (int n = 0; n < 6; n++) {
        int o = n * 16 + lmod;
        gv[n] = gnext[o];
        bv2[n] = bnext[o];
        pb[n] = pwb[o];
    }
    #pragma unroll
    for (int n = 0; n < 6; n++) {
        int o = n * 16 + lmod;
        #pragma unroll
        for (int r = 0; r < 4; r++) {
            int sr = m0 + ldiv * 4 + r;
            size_t row = (size_t)r0 + sr;
            float base = in[row * 96 + o] * SQRTD + pe[(s0 + sr) * 96 + o];
            acc[n][r] = base + fmaxf(acc[n][r] + pb[n], 0.f);
        }
    }
    #pragma unroll
    for (int r = 0; r < 4; r++) {
        float sm = 0.f, qq = 0.f;
        #pragma unroll
        for (int n = 0; n < 6; n++) {
            sm += acc[n][r];
            qq += acc[n][r] * acc[n][r];
        }
        #pragma unroll
        for (int st = 1; st <= 8; st <<= 1) {
            sm += __shfl_xor(sm, st);
            qq += __shfl_xor(qq, st);
        }
        float mean = sm * (1.0f / D);
        float var = qq * (1.0f / D) - mean * mean;
        float rstd = rsqrtf(var + 1e-5f);
        size_t row = (size_t)r0 + m0 + ldiv * 4 + r;
        #pragma unroll
        for (int n = 0; n < 6; n++) {
            int o = n * 16 + lmod;
            xout[row * 96 + o] = acc[n][r];
            lnout[row * 96 + o] = f2h((acc[n][r] - mean) * rstd * gv[n] + bv2[n]);
        }
    }
}

// ---------------- mid conv layer ----------------
__global__ void conv2(const float* __restrict__ xin, const us* __restrict__ lnin,
                      float* __restrict__ xout, us* __restrict__ lnout,
                      const float* __restrict__ dwW, const float* __restrict__ dwB,
                      const us* __restrict__ pwW, const float* __restrict__ pwb,
                      const float* __restrict__ gnext, const float* __restrict__ bnext) {
    __shared__ us dwb_s[64 * 104];
    __shared__ float lw[96 * 8];
    int tid = threadIdx.x;
    int wave = tid >> 6, lane = tid & 63;
    int r0 = blockIdx.x * 64;
    int b = r0 / S, s0 = r0 % S;

    for (int i = tid; i < 96 * KW; i += 256) lw[(i / KW) * 8 + (i % KW)] = dwW[i];
    __syncthreads();

    for (int u = tid; u < 768; u += 256) {
        int j = u / 12, c0 = (u - (u / 12) * 12) * 8;
        float acc[8];
        #pragma unroll
        for (int j2 = 0; j2 < 8; j2++) acc[j2] = dwB[c0 + j2];
        #pragma unroll
        for (int k = 0; k < KW; k++) {
            int ss = s0 + j + k - 3;
            if ((unsigned)ss < (unsigned)S) {
                f16x8 v = ldh(lnin + ((size_t)b * S + ss) * 96 + c0);
                #pragma unroll
                for (int j2 = 0; j2 < 8; j2++) acc[j2] += (float)v[j2] * lw[(c0 + j2) * 8 + k];
            }
        }
        us8 o;
        #pragma unroll
        for (int j2 = 0; j2 < 8; j2++) o[j2] = f2h(acc[j2]);
        *reinterpret_cast<us8*>(&dwb_s[j * 104 + c0]) = o;
    }
    __syncthreads();

    int lmod = lane & 15, ldiv = lane >> 4, m0 = wave * 16;
    f32x4 acc[6] = {};
    #pragma unroll
    for (int kk = 0; kk < 3; kk++) {
        f16x8 af = ldh(&dwb_s[(m0 + lmod) * 104 + kk * 32 + ldiv * 8]);
        #pragma unroll
        for (int n = 0; n < 6; n++) {
            f16x8 bf = ldh(pwW + (size_t)((n * 3 + kk) * 64) * 8 + lane * 8);
            acc[n] = __builtin_amdgcn_mfma_f32_16x16x32_f16(af, bf, acc[n], 0, 0, 0);
        }
    }

    float gv[6], bv2[6], pb[6];
    #pragma unroll
    for (int n = 0; n < 6; n++) {
        int o = n * 16 + lmod;
        gv[n] = gnext[o];
        bv2[n] = bnext[o];
        pb[n] = pwb[o];
    }
    #pragma unroll
    for (int n = 0; n < 6; n++) {
        #pragma unroll
        for (int r = 0; r < 4; r++) {
            size_t row = (size_t)r0 + m0 + ldiv * 4 + r;
            acc[n][r] = xin[row * 96 + n * 16 + lmod] + fmaxf(acc[n][r] + pb[n], 0.f);
        }
    }
    #pragma unroll
    for (int r = 0; r < 4; r++) {
        float sm = 0.f, qq = 0.f;
        #pragma unroll
        for (int n = 0; n < 6; n++) {
            sm += acc[n][r];
            qq += acc[n][r] * acc[n][r];
        }
        #pragma unroll
        for (int st = 1; st <= 8; st <<= 1) {
            sm += __shfl_xor(sm, st);
            qq += __shfl_xor(qq, st);
        }
        float mean = sm * (1.0f / D);
        float var = qq * (1.0f / D) - mean * mean;
        float rstd = rsqrtf(var + 1e-5f);
        size_t row = (size_t)r0 + m0 + ldiv * 4 + r;
        #pragma unroll
        for (int n = 0; n < 6; n++) {
            int o = n * 16 + lmod;
            xout[row * 96 + o] = acc[n][r];
            lnout[row * 96 + o] = f2h((acc[n][r] - mean) * rstd * gv[n] + bv2[n]);
        }
    }
}

// ---------------- conv3 + K/V' projection fused (V chunk-major layout) ----------------
__global__ void conv3p(const float* __restrict__ xin, const us* __restrict__ lnin,
                       float* __restrict__ xout, us* __restrict__ lnout,
                       const float* __restrict__ dwW, const float* __restrict__ dwB,
                       const us* __restrict__ pwW, const float* __restrict__ pwb,
                       const float* __restrict__ gnext, const float* __restrict__ bnext,
                       const us* __restrict__ wkS, const us* __restrict__ wvoS,
                       us* __restrict__ Kall, us* __restrict__ Vall) {
    __shared__ float lw[96 * 8];
    __shared__ us stg[96 * 72];
    __shared__ us lnstg[64 * 104];
    int tid = threadIdx.x;
    int wave = tid >> 6, lane = tid & 63;
    int lmod = lane & 15, ldiv = lane >> 4, m0 = wave * 16;
    int r0 = blockIdx.x * 64;
    int b = r0 / S, s0 = r0 % S;

    for (int i = tid; i < 96 * KW; i += 256) lw[(i / KW) * 8 + (i % KW)] = dwW[i];
    __syncthreads();

    for (int u = tid; u < 768; u += 256) {
        int j = u / 12, c0 = (u - (u / 12) * 12) * 8;
        float acc[8];
        #pragma unroll
        for (int j2 = 0; j2 < 8; j2++) acc[j2] = dwB[c0 + j2];
        #pragma unroll
        for (int k = 0; k < KW; k++) {
            int ss = s0 + j + k - 3;
            if ((unsigned)ss < (unsigned)S) {
                f16x8 v = ldh(lnin + ((size_t)b * S + ss) * 96 + c0);
                #pragma unroll
                for (int j2 = 0; j2 < 8; j2++) acc[j2] += (float)v[j2] * lw[(c0 + j2) * 8 + k];
            }
        }
        us8 o;
        #pragma unroll
        for (int j2 = 0; j2 < 8; j2++) o[j2] = f2h(acc[j2]);
        *reinterpret_cast<us8*>(&stg[j * 104 + c0]) = o;
    }
    __syncthreads();

    f32x4 acc[6] = {};
    #pragma unroll
    for (int kk = 0; kk < 3; kk++) {
        f16x8 af = ldh(&stg[(m0 + lmod) * 104 + kk * 32 + ldiv * 8]);
        #pragma unroll
        for (int n = 0; n < 6; n++) {
            f16x8 bf = ldh(pwW + (size_t)((n * 3 + kk) * 64) * 8 + lane * 8);
            acc[n] = __builtin_amdgcn_mfma_f32_16x16x32_f16(af, bf, acc[n], 0, 0, 0);
        }
    }

    float gv[6], bv2[6], pb[6];
    #pragma unroll
    for (int n = 0; n < 6; n++) {
        int o = n * 16 + lmod;
        gv[n] = gnext[o];
        bv2[n] = bnext[o];
        pb[n] = pwb[o];
    }
    #pragma unroll
    for (int n = 0; n < 6; n++) {
        #pragma unroll
        for (int r = 0; r < 4; r++) {
            size_t row = (size_t)r0 + m0 + ldiv * 4 + r;
            acc[n][r] = xin[row * 96 + n * 16 + lmod] + fmaxf(acc[n][r] + pb[n], 0.f);
        }
    }
    #pragma unroll
    for (int r = 0; r < 4; r++) {
        float sm = 0.f, qq = 0.f;
        #pragma unroll
        for (int n = 0; n < 6; n++) {
            sm += acc[n][r];
            qq += acc[n][r] * acc[n][r];
        }
        #pragma unroll
        for (int st = 1; st <= 8; st <<= 1) {
            sm += __shfl_xor(sm, st);
            qq += __shfl_xor(qq, st);
        }
        float mean = sm * (1.0f / D);
        float var = qq * (1.0f / D) - mean * mean;
        float rstd = rsqrtf(var + 1e-5f);
        size_t row = (size_t)r0 + m0 + ldiv * 4 + r;
        #pragma unroll
        for (int n = 0; n < 6; n++) {
            int o = n * 16 + lmod;
            xout[row * 96 + o] = acc[n][r];
            us hv = f2h((acc[n][r] - mean) * rstd * gv[n] + bv2[n]);
            lnout[row * 96 + o] = hv;
            lnstg[(m0 + ldiv * 4 + r) * 104 + o] = hv;
        }
    }
    __syncthreads();

    f16x8 af[3];
    #pragma unroll
    for (int kk = 0; kk < 3; kk++)
        af[kk] = ldh(&lnstg[(m0 + lmod) * 104 + kk * 32 + ldiv * 8]);

    for (int hd = 0; hd < H; hd++) {
        // ---- K ----
        f32x4 ka[6] = {};
        #pragma unroll
        for (int kk = 0; kk < 3; kk++)
            #pragma unroll
            for (int n = 0; n < 6; n++) {
                f16x8 bf = ldh(wkS + (size_t)hd * D * D + (size_t)((n * 3 + kk) * 64) * 8 + lane * 8);
                ka[n] = __builtin_amdgcn_mfma_f32_16x16x32_f16(af[kk], bf, ka[n], 0, 0, 0);
            }
        __syncthreads();
        us* kT = stg + wave * 1664;
        #pragma unroll
        for (int n = 0; n < 6; n++)
            #pragma unroll
            for (int r = 0; r < 4; r++)
                kT[(ldiv * 4 + r) * 104 + n * 16 + lmod] = f2h(ka[n][r]);
        int t0 = (r0 % S) / 16 + wave;
        us* dst = Kall + (size_t)hd * NTOT + ((size_t)(b * 24 + t0) * 3) * 512;
        #pragma unroll
        for (int kk = 0; kk < 3; kk++) {
            us8 v = *reinterpret_cast<const us8*>(&kT[lmod * 104 + kk * 32 + ldiv * 8]);
            *reinterpret_cast<us8*>(dst + kk * 512 + lane * 8) = v;
        }
        // ---- V' ---- (chunk-major: [b][cblk][n][kk][lane][8])
        f32x4 va[6] = {};
        #pragma unroll
        for (int kk = 0; kk < 3; kk++)
            #pragma unroll
            for (int n = 0; n < 6; n++) {
                f16x8 bf =
                    ldh(wvoS + (size_t)hd * D * D + (size_t)((n * 3 + kk) * 64) * 8 + lane * 8);
                va[n] = __builtin_amdgcn_mfma_f32_16x16x32_f16(af[kk], bf, va[n], 0, 0, 0);
            }
        __syncthreads();
        #pragma unroll
        for (int n = 0; n < 6; n++)
            #pragma unroll
            for (int r = 0; r < 4; r++)
                stg[(n * 16 + lmod) * 72 + m0 + ldiv * 4 + r] = f2h(va[n][r]);
        __syncthreads();
        int cblk = (r0 % S) / 64;
        us* dsth = Vall + (size_t)hd * NTOT;
        #pragma unroll
        for (int n = 0; n < 6; n++)
            #pragma unroll
            for (int kk = 0; kk < 2; kk++) {
                us8 v =
                    *reinterpret_cast<const us8*>(&stg[(n * 16 + lmod) * 72 + kk * 32 + ldiv * 8]);
                *reinterpret_cast<us8*>(
                    dsth + ((size_t)((b * 6 + cblk) * 6 + n) * 2 + kk) * 512 + lane * 8) = v;
            }
    }
}

// ---------------- block-cooperative LDS-staged attention ----------------
__global__ __launch_bounds__(256, 2) void attn_g(const us* __restrict__ h16,
                                                 const us* __restrict__ wqS,
                                                 const us* __restrict__ Kall,
                                                 const us* __restrict__ Vall,
                                                 us* __restrict__ xpart) {
    __shared__ us Kb[2][6144];
    __shared__ us Vb[2][6144];
    __shared__ us Pq[4][3328];
    int tid = threadIdx.x, wave = tid >> 6, lane = tid & 63;
    int lmod = lane & 15, ldiv = lane >> 4;
    int p = blockIdx.x;
    int gl = (p & 7) * 192 + (p >> 3);  // XCD swizzle, 1536 = 8*192
    int qt = gl % 3;
    int bh = gl / 3;
    int b = bh >> 2, hd = bh & 3;
    size_t rowbase = (size_t)b * S + qt * 128 + wave * 32;

    const us* Kh = Kall + (size_t)hd * NTOT + (size_t)b * 24 * 1536;
    const us* Vh = Vall + (size_t)hd * NTOT + (size_t)b * 36 * 1024;
    us* P = Pq[wave];

    us8 kst[3];
    #pragma unroll
    for (int j = 0; j < 3; j++)
        kst[j] = *reinterpret_cast<const us8*>(Kh + (size_t)(j * 256 + tid) * 8);

    f32x4 qa0[6] = {}, qa1[6] = {};
    #pragma unroll
    for (int kk = 0; kk < 3; kk++) {
        f16x8 a0 = ldh(h16 + (rowbase + lmod) * 96 + kk * 32 + ldiv * 8);
        f16x8 a1 = ldh(h16 + (rowbase + 16 + lmod) * 96 + kk * 32 + ldiv * 8);
        #pragma unroll
        for (int n = 0; n < 6; n++) {
            f16x8 bf = ldh(wqS + (size_t)hd * D * D + (size_t)((n * 3 + kk) * 64) * 8 + lane * 8);
            qa0[n] = __builtin_amdgcn_mfma_f32_16x16x32_f16(a0, bf, qa0[n], 0, 0, 0);
            qa1[n] = __builtin_amdgcn_mfma_f32_16x16x32_f16(a1, bf, qa1[n], 0, 0, 0);
        }
    }
    #pragma unroll
    for (int n = 0; n < 6; n++)
        #pragma unroll
        for (int r = 0; r < 4; r++) {
            P[(ldiv * 4 + r) * 104 + n * 16 + lmod] = f2h(qa0[n][r]);
            P[(16 + ldiv * 4 + r) * 104 + n * 16 + lmod] = f2h(qa1[n][r]);
        }
    f16x8 aq0[3], aq1[3];
    #pragma unroll
    for (int kk = 0; kk < 3; kk++) {
        aq0[kk] = ldh(&P[lmod * 104 + kk * 32 + ldiv * 8]);
        aq1[kk] = ldh(&P[(16 + lmod) * 104 + kk * 32 + ldiv * 8]);
    }
    #pragma unroll
    for (int j = 0; j < 3; j++)
        *reinterpret_cast<us8*>(&Kb[0][(j * 256 + tid) * 8]) = kst[j];
    __syncthreads();

    // ---- pass 1: row max ----
    f32x4 mx0 = {-1e30f, -1e30f, -1e30f, -1e30f}, mx1 = mx0;
    for (int c = 0; c < 6; c++) {
        int cur = c & 1, nxt = cur ^ 1;
        us8 kn[3], vn[3];
        bool last = (c == 5);
        if (!last) {
            #pragma unroll
            for (int j = 0; j < 3; j++)
                kn[j] = *reinterpret_cast<const us8*>(Kh + (size_t)(c + 1) * 6144 +
                                                      (size_t)(j * 256 + tid) * 8);
        } else {
            #pragma unroll
            for (int j = 0; j < 3; j++) {
                kn[j] = *reinterpret_cast<const us8*>(Kh + (size_t)(j * 256 + tid) * 8);
                vn[j] = *reinterpret_cast<const us8*>(Vh + (size_t)(j * 256 + tid) * 8);
            }
        }
        __builtin_amdgcn_s_setprio(1);
        f32x4 s0[4] = {}, s1[4] = {};
        #pragma unroll
        for (int nt = 0; nt < 4; nt++)
            #pragma unroll
            for (int kk = 0; kk < 3; kk++) {
                f16x8 bf = ldh(&Kb[cur][(nt * 3 + kk) * 512 + lane * 8]);
                s0[nt] = __builtin_amdgcn_mfma_f32_16x16x32_f16(aq0[kk], bf, s0[nt], 0, 0, 0);
                s1[nt] = __builtin_amdgcn_mfma_f32_16x16x32_f16(aq1[kk], bf, s1[nt], 0, 0, 0);
            }
        __builtin_amdgcn_s_setprio(0);
        #pragma unroll
        for (int nt = 0; nt < 4; nt++)
            #pragma unroll
            for (int r = 0; r < 4; r++) {
                mx0[r] = fmaxf(mx0[r], s0[nt][r]);
                mx1[r] = fmaxf(mx1[r], s1[nt][r]);
            }
        int wb = last ? 0 : nxt;
        #pragma unroll
        for (int j = 0; j < 3; j++)
            *reinterpret_cast<us8*>(&Kb[wb][(j * 256 + tid) * 8]) = kn[j];
        if (last) {
            #pragma unroll
            for (int j = 0; j < 3; j++)
                *reinterpret_cast<us8*>(&Vb[0][(j * 256 + tid) * 8]) = vn[j];
        }
        __syncthreads();
    }
    #pragma unroll
    for (int st = 1; st <= 8; st <<= 1)
        #pragma unroll
        for (int r = 0; r < 4; r++) {
            mx0[r] = fmaxf(mx0[r], __shfl_xor(mx0[r], st));
            mx1[r] = fmaxf(mx1[r], __shfl_xor(mx1[r], st));
        }

    // ---- pass 2: scores -> exp -> PV ----
    f32x4 oacc0[6] = {}, oacc1[6] = {};
    f32x4 l0v = {}, l1v = {};
    for (int c = 0; c < 6; c++) {
        int cur = c & 1, nxt = cur ^ 1;
        us8 kn[3], vn[3];
        if (c < 5) {
            #pragma unroll
            for (int j = 0; j < 3; j++) {
                kn[j] = *reinterpret_cast<const us8*>(Kh + (size_t)(c + 1) * 6144 +
                                                      (size_t)(j * 256 + tid) * 8);
                vn[j] = *reinterpret_cast<const us8*>(Vh + (size_t)(c + 1) * 6144 +
                                                      (size_t)(j * 256 + tid) * 8);
            }
        }
        __builtin_amdgcn_s_setprio(1);
        f32x4 s0[4] = {}, s1[4] = {};
        #pragma unroll
        for (int nt = 0; nt < 4; nt++)
            #pragma unroll
            for (int kk = 0; kk < 3; kk++) {
                f16x8 bf = ldh(&Kb[cur][(nt * 3 + kk) * 512 + lane * 8]);
                s0[nt] = __builtin_amdgcn_mfma_f32_16x16x32_f16(aq0[kk], bf, s0[nt], 0, 0, 0);
                s1[nt] = __builtin_amdgcn_mfma_f32_16x16x32_f16(aq1[kk], bf, s1[nt], 0, 0, 0);
            }
        __builtin_amdgcn_s_setprio(0);
        #pragma unroll
        for (int nt = 0; nt < 4; nt++)
            #pragma unroll
            for (int r = 0; r < 4; r++) {
                float p0 = __expf(s0[nt][r] - mx0[r]);
                float p1 = __expf(s1[nt][r] - mx1[r]);
                l0v[r] += p0;
                l1v[r] += p1;
                P[(ldiv * 4 + r) * 72 + nt * 16 + lmod] = f2h(p0);
                P[(16 + ldiv * 4 + r) * 72 + nt * 16 + lmod] = f2h(p1);
            }
        __builtin_amdgcn_s_setprio(1);
        #pragma unroll
        for (int kk = 0; kk < 2; kk++) {
            f16x8 pf0 = ldh(&P[lmod * 72 + kk * 32 + ldiv * 8]);
            f16x8 pf1 = ldh(&P[(16 + lmod) * 72 + kk * 32 + ldiv * 8]);
            #pragma unroll
            for (int n = 0; n < 6; n++) {
                f16x8 bf = ldh(&Vb[cur][(n * 2 + kk) * 512 + lane * 8]);
                oacc0[n] = __builtin_amdgcn_mfma_f32_16x16x32_f16(pf0, bf, oacc0[n], 0, 0, 0);
                oacc1[n] = __builtin_amdgcn_mfma_f32_16x16x32_f16(pf1, bf, oacc1[n], 0, 0, 0);
            }
        }
        __builtin_amdgcn_s_setprio(0);
        if (c < 5) {
            #pragma unroll
            for (int j = 0; j < 3; j++) {
                *reinterpret_cast<us8*>(&Kb[nxt][(j * 256 + tid) * 8]) = kn[j];
                *reinterpret_cast<us8*>(&Vb[nxt][(j * 256 + tid) * 8]) = vn[j];
            }
            __syncthreads();
        }
    }
    #pragma unroll
    for (int st = 1; st <= 8; st <<= 1)
        #pragma unroll
        for (int r = 0; r < 4; r++) {
            l0v[r] += __shfl_xor(l0v[r], st);
            l1v[r] += __shfl_xor(l1v[r], st);
        }

    us* xp = xpart + (size_t)hd * NTOT;
    #pragma unroll
    for (int r = 0; r < 4; r++) {
        float inv0 = 1.f / l0v[r];
        float inv1 = 1.f / l1v[r];
        #pragma unroll
        for (int n = 0; n < 6; n++) {
            xp[(rowbase + ldiv * 4 + r) * 96 + n * 16 + lmod] = f2h(oacc0[n][r] * inv0);
            xp[(rowbase + 16 + ldiv * 4 + r) * 96 + n * 16 + lmod] = f2h(oacc1[n][r] * inv1);
        }
    }
}

// ---------------- fused head-reduce + LN + FFN ----------------
__global__ void ffn_ln(const float* __restrict__ x, const us* __restrict__ xpart,
                       const float* __restrict__ gln, const float* __restrict__ bln,
                       const us* __restrict__ w1S, const float* __restrict__ b1,
                       const us* __restrict__ w2S, const float* __restrict__ b2,
                       float* __restrict__ out) {
    __shared__ float xf[64 * 96];
    __shared__ us lnb[64 * 104];
    __shared__ us mid[64 * 72];
    int tid = threadIdx.x, wave = tid >> 6, lane = tid & 63;
    int lmod = lane & 15, ldiv = lane >> 4, m0 = wave * 16;
    int row0 = blockIdx.x * 64;

    for (int i = wave; i < 64; i += 4) {
        size_t ro = (size_t)(row0 + i) * 96;
        float v0 = x[ro + lane];
        float v1 = (lane < 32) ? x[ro + 64 + lane] : 0.f;
        #pragma unroll
        for (int h = 0; h < H; h++) {
            const us* xp = xpart + (size_t)h * NTOT + ro;
            v0 += (float)__builtin_bit_cast(_Float16, xp[lane]);
            if (lane < 32) v1 += (float)__builtin_bit_cast(_Float16, xp[64 + lane]);
        }
        xf[i * 96 + lane] = v0;
        if (lane < 32) xf[i * 96 + 64 + lane] = v1;
        float sm = v0 + v1, q = v0 * v0 + v1 * v1;
        for (int off = 32; off > 0; off >>= 1) {
            sm += __shfl_xor(sm, off);
            q += __shfl_xor(q, off);
        }
        float mean = sm * (1.0f / D);
        float var = q * (1.0f / D) - mean * mean;
        float rstd = rsqrtf(var + 1e-5f);
        lnb[i * 104 + lane] = f2h((v0 - mean) * rstd * gln[lane] + bln[lane]);
        if (lane < 32)
            lnb[i * 104 + 64 + lane] = f2h((v1 - mean) * rstd * gln[lane + 64] + bln[lane + 64]);
    }
    __syncthreads();

    f32x4 a3[3] = {};
    #pragma unroll
    for (int kk = 0; kk < 3; kk++) {
        f16x8 af = ldh(&lnb[(m0 + lmod) * 104 + kk * 32 + ldiv * 8]);
        #pragma unroll
        for (int n = 0; n < 3; n++) {
            f16x8 bf = ldh(w1S + (size_t)((n * 3 + kk) * 64) * 8 + lane * 8);
            a3[n] = __builtin_amdgcn_mfma_f32_16x16x32_f16(af, bf, a3[n], 0, 0, 0);
        }
    }
    #pragma unroll
    for (int n = 0; n < 3; n++) {
        float bv = b1[n * 16 + lmod];
        #pragma unroll
        for (int r = 0; r < 4; r++) {
            float v = a3[n][r] + bv;
            mid[(m0 + ldiv * 4 + r) * 72 + n * 16 + lmod] = f2h(1.f / (1.f + __expf(-v)));
        }
    }
    #pragma unroll
    for (int r = 0; r < 4; r++) mid[(m0 + ldiv * 4 + r) * 72 + 48 + lmod] = 0;
    __syncthreads();

    f32x4 a6[6] = {};
    #pragma unroll
    for (int kk = 0; kk < 2; kk++) {
        f16x8 af = ldh(&mid[(m0 + lmod) * 72 + kk * 32 + ldiv * 8]);
        #pragma unroll
        for (int n = 0; n < 6; n++) {
            f16x8 bf = ldh(w2S + (size_t)((n * 2 + kk) * 64) * 8 + lane * 8);
            a6[n] = __builtin_amdgcn_mfma_f32_16x16x32_f16(af, bf, a6[n], 0, 0, 0);
        }
    }
    #pragma unroll
    for (int n = 0; n < 6; n++) {
        int o = n * 16 + lmod;
        float bv = b2[o];
        #pragma unroll
        for (int r = 0; r < 4; r++) {
            int sr = m0 + ldiv * 4 + r;
            out[(size_t)(row0 + sr) * 96 + o] = xf[sr * 96 + o] + a6[n][r] + bv;
        }
    }
}

extern "C" void kernel_launch(void* const* d_in, const int* in_sizes, int n_in,
                              void* d_out, int out_size, void* d_ws, size_t ws_size,
                              hipStream_t stream) {
    const float* in   = (const float*)d_in[0];
    const float* cdw  = (const float*)d_in[2];
    const float* cdwb = (const float*)d_in[3];
    const float* cpw  = (const float*)d_in[4];
    const float* cpwb = (const float*)d_in[5];
    const float* WQ   = (const float*)d_in[6];
    const float* WK   = (const float*)d_in[7];
    const float* WV   = (const float*)d_in[8];
    const float* WO   = (const float*)d_in[9];
    const float* w1   = (const float*)d_in[10];
    const float* b1   = (const float*)d_in[11];
    const float* w2   = (const float*)d_in[12];
    const float* b2   = (const float*)d_in[13];
    const float* lng  = (const float*)d_in[14];
    const float* lnb  = (const float*)d_in[15];
    float* out = (float*)d_out;
    float* ws = (float*)d_ws;

    float* xA  = ws;
    float* xB  = xA + NTOT;
    float* pe  = xB + NTOT;
    us* lnA    = (us*)(pe + S * D);
    us* lnB    = lnA + NTOT;
    us* Kall   = lnB + NTOT;               // [H][B][24][3][64][8]
    us* Vall   = Kall + (size_t)H * NTOT;  // [H][B][6 c][6 n][2 kk][64][8]
    us* xpart  = Vall + (size_t)H * NTOT;  // [H][ROWS][96]
    us* wqS    = xpart + (size_t)H * NTOT;
    us* wkS    = wqS + H * D * D;
    us* wvoS   = wkS + H * D * D;
    us* pwS    = wvoS + H * D * D;
    us* w1S    = pwS + L * D * D;
    us* w2S    = w1S + 48 * 96;
    // total ~= 170 MB (< 256 MB ws)

    pe_kernel<<<(S * D + 255) / 256, 256, 0, stream>>>(pe);
    prep_w<<<(H * D * D + 255) / 256, 256, 0, stream>>>(WQ, WK, cpw, w1, w2,
                                                        wqS, wkS, pwS, w1S, w2S);
    prep_wvo<<<H * 6, 256, 0, stream>>>(WV, WO, wvoS);

    conv0f<<<ROWS / 64, 256, 0, stream>>>(in, pe, lng, lnb, xA, lnB,
                                          cdw, cdwb, pwS, cpwb, lng + D, lnb + D);
    conv2<<<ROWS / 64, 256, 0, stream>>>(xA, lnB, xB, lnA, cdw + D * KW, cdwb + D,
                                         pwS + D * D, cpwb + D, lng + 2 * D, lnb + 2 * D);
    conv2<<<ROWS / 64, 256, 0, stream>>>(xB, lnA, xA, lnB, cdw + 2 * D * KW, cdwb + 2 * D,
                                         pwS + 2 * D * D, cpwb + 2 * D, lng + 3 * D,
                                         lnb + 3 * D);
    conv3p<<<ROWS / 64, 256, 0, stream>>>(xA, lnB, xB, lnA, cdw + 3 * D * KW, cdwb + 3 * D,
                                          pwS + 3 * D * D, cpwb + 3 * D, lng + 4 * D,
                                          lnb + 4 * D, wkS, wvoS, Kall, Vall);

    // lnA == h16, xB == x4
    attn_g<<<1536, 256, 0, stream>>>(lnA, wqS, Kall, Vall, xpart);

    ffn_ln<<<ROWS / 64, 256, 0, stream>>>(xB, xpart, lng + 5 * D, lnb + 5 * D,
                                          w1S, b1, w2S, b2, out);
}